// Round 1
// baseline (1459.827 us; speedup 1.0000x reference)
//
#include <hip/hip_runtime.h>

// Problem constants (AttnBlock3D): x (B=2, C=256, D=H=W=16), N = 4096 spatial.
#define C_DIM 256
#define N_SP  4096
#define B_DIM 2
#define CPG   8        // channels per group (256/32)
#define EPS_GN 1e-5f

// ---------------------------------------------------------------------------
// GroupNorm: one block per (batch, group). Stats over 8*4096 = 32768 elems.
// ---------------------------------------------------------------------------
__global__ __launch_bounds__(256) void gn_kernel(const float* __restrict__ x,
    const float* __restrict__ w, const float* __restrict__ bgn,
    float* __restrict__ h) {
  const int bg = blockIdx.x;            // 0..63
  const int b = bg >> 5, g = bg & 31;
  const size_t base = ((size_t)b * C_DIM + (size_t)g * CPG) * N_SP;
  const float* xp = x + base;
  float* hp = h + base;
  const int tid = threadIdx.x;
  const int TOT = CPG * N_SP;           // 32768
  float s = 0.f, ss = 0.f;
  for (int i = tid; i < TOT; i += 256) {
    float v = xp[i];
    s += v; ss += v * v;
  }
#pragma unroll
  for (int off = 32; off > 0; off >>= 1) {
    s  += __shfl_down(s, off);
    ss += __shfl_down(ss, off);
  }
  __shared__ float rs[4], rss[4];
  __shared__ float smean, srstd;
  const int wv = tid >> 6, ln = tid & 63;
  if (ln == 0) { rs[wv] = s; rss[wv] = ss; }
  __syncthreads();
  if (tid == 0) {
    float S  = rs[0] + rs[1] + rs[2] + rs[3];
    float SS = rss[0] + rss[1] + rss[2] + rss[3];
    float mean = S / (float)TOT;
    float var  = SS / (float)TOT - mean * mean;
    smean = mean;
    srstd = rsqrtf(var + EPS_GN);
  }
  __syncthreads();
  const float mean = smean, rstd = srstd;
  for (int i = tid; i < TOT; i += 256) {
    int c = g * CPG + (i >> 12);        // i / 4096
    hp[i] = (xp[i] - mean) * rstd * w[c] + bgn[c];
  }
}

// ---------------------------------------------------------------------------
// GEMM: Y[o,n] = sum_c W[o,c] X[c,n] + bias[o]  (+ optional residual R)
// W: (256,256) row-major. X,Y,R: (B, 256, 4096), batch = blockIdx.z.
// Tiles: BM=64 x BN=64, BK=32; 256 threads, 4x4 micro-tile per thread.
// ---------------------------------------------------------------------------
#define BM 64
#define BN 64
#define BK 32
__global__ __launch_bounds__(256) void gemm_kernel(const float* __restrict__ W,
    const float* __restrict__ bias, const float* __restrict__ X,
    float* __restrict__ Y, const float* __restrict__ R) {
  __shared__ float As[BM][BK + 1];   // +1 pad: conflict-free strided reads
  __shared__ float Bs[BK][BN];
  const size_t boff = (size_t)blockIdx.z * C_DIM * N_SP;
  const float* Xb = X + boff;
  float* Yb = Y + boff;
  const int bn = blockIdx.x * BN, bm = blockIdx.y * BM;
  const int tid = threadIdx.x;
  const int tm = (tid >> 4) << 2;    // 0..60
  const int tn = (tid & 15) << 2;    // 0..60
  float acc[4][4] = {};
  for (int k0 = 0; k0 < C_DIM; k0 += BK) {
    for (int i = tid; i < BM * BK; i += 256) {
      int m = i >> 5, kk = i & 31;
      As[m][kk] = W[(size_t)(bm + m) * C_DIM + k0 + kk];
    }
    for (int i = tid; i < BK * BN; i += 256) {
      int kk = i >> 6, n = i & 63;
      Bs[kk][n] = Xb[(size_t)(k0 + kk) * N_SP + bn + n];
    }
    __syncthreads();
#pragma unroll
    for (int kk = 0; kk < BK; ++kk) {
      float a0 = As[tm + 0][kk], a1 = As[tm + 1][kk];
      float a2 = As[tm + 2][kk], a3 = As[tm + 3][kk];
      float4 bv = *(const float4*)&Bs[kk][tn];
      acc[0][0] += a0 * bv.x; acc[0][1] += a0 * bv.y; acc[0][2] += a0 * bv.z; acc[0][3] += a0 * bv.w;
      acc[1][0] += a1 * bv.x; acc[1][1] += a1 * bv.y; acc[1][2] += a1 * bv.z; acc[1][3] += a1 * bv.w;
      acc[2][0] += a2 * bv.x; acc[2][1] += a2 * bv.y; acc[2][2] += a2 * bv.z; acc[2][3] += a2 * bv.w;
      acc[3][0] += a3 * bv.x; acc[3][1] += a3 * bv.y; acc[3][2] += a3 * bv.z; acc[3][3] += a3 * bv.w;
    }
    __syncthreads();
  }
#pragma unroll
  for (int i = 0; i < 4; ++i) {
    int m = bm + tm + i;
    float bi = bias[m];
#pragma unroll
    for (int j = 0; j < 4; ++j) {
      int n = bn + tn + j;
      float v = acc[i][j] + bi;
      if (R) v += R[boff + (size_t)m * N_SP + n];
      Yb[(size_t)m * N_SP + n] = v;
    }
  }
}

// ---------------------------------------------------------------------------
// Flash attention, fp32. q,k,v,ao: (B, 256, 4096) channel-major.
// attn[n,m] = softmax_m( (1/16) * sum_c q[c,n] k[c,m] );  ao[c,n] = sum_m attn*v[c,m]
// One block per 32 queries: grid (128, B). 256 threads: qi = tid>>3, ti = tid&7.
// LDS ~104 KB -> 1 block/CU (gfx950 has 160 KB/CU).
// ---------------------------------------------------------------------------
#define QT 32
#define KT 32
#define LSTR 260   // row stride (floats); 260*4 % 16 == 0 keeps float4 aligned
__global__ __launch_bounds__(256) void attn_kernel(const float* __restrict__ q,
    const float* __restrict__ k, const float* __restrict__ v,
    float* __restrict__ ao) {
  __shared__ float q_lds[QT][LSTR];
  __shared__ float k_lds[KT][LSTR];
  __shared__ float v_lds[KT][LSTR];
  __shared__ float s_lds[QT][33];
  const int b = blockIdx.y;
  const int q0 = blockIdx.x * QT;
  const size_t base = (size_t)b * C_DIM * N_SP;
  const float* qp = q + base;
  const float* kp = k + base;
  const float* vp = v + base;
  const int tid = threadIdx.x;
  const int qi = tid >> 3;   // 0..31
  const int ti = tid & 7;    // 0..7

  for (int i = tid; i < QT * C_DIM; i += 256) {
    int c = i >> 5, j = i & 31;
    q_lds[j][c] = qp[(size_t)c * N_SP + q0 + j];
  }
  float O[32];
#pragma unroll
  for (int i = 0; i < 32; ++i) O[i] = 0.f;
  float m_run = -1e30f, l_run = 0.f;
  __syncthreads();

  for (int k0 = 0; k0 < N_SP; k0 += KT) {
    for (int i = tid; i < KT * C_DIM; i += 256) {
      int c = i >> 5, j = i & 31;
      k_lds[j][c] = kp[(size_t)c * N_SP + k0 + j];
      v_lds[j][c] = vp[(size_t)c * N_SP + k0 + j];
    }
    __syncthreads();

    // S[qi][ti + 8j] = scale * <q[:,qi], k[:,kj]>
    float acc[4] = {0.f, 0.f, 0.f, 0.f};
    for (int c0 = 0; c0 < C_DIM; c0 += 4) {
      float4 qv = *(const float4*)&q_lds[qi][c0];
#pragma unroll
      for (int j = 0; j < 4; ++j) {
        float4 kv = *(const float4*)&k_lds[ti + 8 * j][c0];
        acc[j] += qv.x * kv.x + qv.y * kv.y + qv.z * kv.z + qv.w * kv.w;
      }
    }
    float mx = -1e30f;
#pragma unroll
    for (int j = 0; j < 4; ++j) { acc[j] *= 0.0625f; mx = fmaxf(mx, acc[j]); }
#pragma unroll
    for (int off = 1; off < 8; off <<= 1) mx = fmaxf(mx, __shfl_xor(mx, off));
    const float m_new = fmaxf(m_run, mx);
    float p[4]; float ls = 0.f;
#pragma unroll
    for (int j = 0; j < 4; ++j) { p[j] = __expf(acc[j] - m_new); ls += p[j]; }
#pragma unroll
    for (int off = 1; off < 8; off <<= 1) ls += __shfl_xor(ls, off);
    const float alpha = __expf(m_run - m_new);
    m_run = m_new;
    l_run = l_run * alpha + ls;
#pragma unroll
    for (int i = 0; i < 32; ++i) O[i] *= alpha;
#pragma unroll
    for (int j = 0; j < 4; ++j) s_lds[qi][ti + 8 * j] = p[j];
    __syncthreads();

    // PV: thread owns qi, channels c = 4*ti + 32*cc + {0..3}
    for (int m = 0; m < KT; ++m) {
      float pm = s_lds[qi][m];
#pragma unroll
      for (int cc = 0; cc < 8; ++cc) {
        float4 vv = *(const float4*)&v_lds[m][4 * ti + 32 * cc];
        O[cc * 4 + 0] += pm * vv.x;
        O[cc * 4 + 1] += pm * vv.y;
        O[cc * 4 + 2] += pm * vv.z;
        O[cc * 4 + 3] += pm * vv.w;
      }
    }
    __syncthreads();
  }

  // Epilogue: normalize by l, transpose through LDS for coalesced store.
  const float inv = 1.f / l_run;
  float* out_lds = &k_lds[0][0];   // 8320 floats >= 8192 needed
#pragma unroll
  for (int cc = 0; cc < 8; ++cc) {
#pragma unroll
    for (int j = 0; j < 4; ++j) {
      int c = 32 * cc + 4 * ti + j;
      out_lds[c * 32 + qi] = O[cc * 4 + j] * inv;
    }
  }
  __syncthreads();
  for (int i = tid; i < QT * C_DIM; i += 256) {
    int c = i >> 5, j = i & 31;
    ao[base + (size_t)c * N_SP + q0 + j] = out_lds[i];
  }
}

// ---------------------------------------------------------------------------
extern "C" void kernel_launch(void* const* d_in, const int* in_sizes, int n_in,
                              void* d_out, int out_size, void* d_ws, size_t ws_size,
                              hipStream_t stream) {
  const float* x   = (const float*)d_in[0];
  const float* gnw = (const float*)d_in[1];
  const float* gnb = (const float*)d_in[2];
  const float* wq  = (const float*)d_in[3];
  const float* bq  = (const float*)d_in[4];
  const float* wk  = (const float*)d_in[5];
  const float* bk  = (const float*)d_in[6];
  const float* wv  = (const float*)d_in[7];
  const float* bv  = (const float*)d_in[8];
  const float* wp  = (const float*)d_in[9];
  const float* bp  = (const float*)d_in[10];
  float* out = (float*)d_out;

  const size_t CN = (size_t)C_DIM * N_SP;   // 1,048,576 floats per batch-plane
  // Workspace layout (fp32): h | q | k | v | ao  -> 5 * B * CN * 4 = 40 MB
  float* h  = (float*)d_ws;
  float* qb = h  + (size_t)B_DIM * CN;
  float* kb = qb + (size_t)B_DIM * CN;
  float* vb = kb + (size_t)B_DIM * CN;
  float* ab = vb + (size_t)B_DIM * CN;

  gn_kernel<<<dim3(B_DIM * 32), dim3(256), 0, stream>>>(x, gnw, gnb, h);

  dim3 gg(N_SP / BN, C_DIM / BM, B_DIM);
  gemm_kernel<<<gg, dim3(256), 0, stream>>>(wq, bq, h, qb, nullptr);
  gemm_kernel<<<gg, dim3(256), 0, stream>>>(wk, bk, h, kb, nullptr);
  gemm_kernel<<<gg, dim3(256), 0, stream>>>(wv, bv, h, vb, nullptr);

  attn_kernel<<<dim3(N_SP / QT, B_DIM), dim3(256), 0, stream>>>(qb, kb, vb, ab);

  gemm_kernel<<<gg, dim3(256), 0, stream>>>(wp, bp, ab, out, x);
}

// Round 2
// 387.188 us; speedup vs baseline: 3.7703x; 3.7703x over previous
//
#include <hip/hip_runtime.h>

#define C_DIM 256
#define N_SP  4096
#define B_DIM 2
#define CPG   8
#define EPS_GN 1e-5f

typedef unsigned short ushort_t;
typedef __attribute__((ext_vector_type(4))) float f32x4;
typedef __attribute__((ext_vector_type(8))) short bf16x8;   // 8 bf16 = 4 VGPR

__device__ inline ushort_t f2bf(float f) {
  union { float f; unsigned u; } v; v.f = f;
  unsigned r = v.u + 0x7FFF + ((v.u >> 16) & 1);   // RNE
  return (ushort_t)(r >> 16);
}

// ---------------------------------------------------------------------------
// GroupNorm (unchanged from verified round-1 kernel)
// ---------------------------------------------------------------------------
__global__ __launch_bounds__(256) void gn_kernel(const float* __restrict__ x,
    const float* __restrict__ w, const float* __restrict__ bgn,
    float* __restrict__ h) {
  const int bg = blockIdx.x;
  const int b = bg >> 5, g = bg & 31;
  const size_t base = ((size_t)b * C_DIM + (size_t)g * CPG) * N_SP;
  const float* xp = x + base;
  float* hp = h + base;
  const int tid = threadIdx.x;
  const int TOT = CPG * N_SP;
  float s = 0.f, ss = 0.f;
  for (int i = tid; i < TOT; i += 256) {
    float v = xp[i];
    s += v; ss += v * v;
  }
#pragma unroll
  for (int off = 32; off > 0; off >>= 1) {
    s  += __shfl_down(s, off);
    ss += __shfl_down(ss, off);
  }
  __shared__ float rs[4], rss[4];
  __shared__ float smean, srstd;
  const int wv = tid >> 6, ln = tid & 63;
  if (ln == 0) { rs[wv] = s; rss[wv] = ss; }
  __syncthreads();
  if (tid == 0) {
    float S  = rs[0] + rs[1] + rs[2] + rs[3];
    float SS = rss[0] + rss[1] + rss[2] + rss[3];
    float mean = S / (float)TOT;
    float var  = SS / (float)TOT - mean * mean;
    smean = mean;
    srstd = rsqrtf(var + EPS_GN);
  }
  __syncthreads();
  const float mean = smean, rstd = srstd;
  for (int i = tid; i < TOT; i += 256) {
    int c = g * CPG + (i >> 12);
    hp[i] = (xp[i] - mean) * rstd * w[c] + bgn[c];
  }
}

// ---------------------------------------------------------------------------
// GEMM: Y[o,n] = sum_c W[o,c] X[c,n] + bias[o]
// MODE 0: fp32 out [o][n] (+ residual)       -> YF
// MODE 1: bf16 out TRANSPOSED [n][o]         -> YB   (for q, k)
// MODE 2: bf16 out natural [o][n]            -> YB   (for v)
// ---------------------------------------------------------------------------
#define BM 64
#define BN 64
#define BK 32
template <int MODE>
__global__ __launch_bounds__(256) void gemm_kernel(const float* __restrict__ W,
    const float* __restrict__ bias, const float* __restrict__ X,
    float* __restrict__ YF, ushort_t* __restrict__ YB,
    const float* __restrict__ R) {
  __shared__ float As[BM][BK + 1];
  __shared__ float Bs[BK][BN];
  const size_t boff = (size_t)blockIdx.z * C_DIM * N_SP;
  const float* Xb = X + boff;
  const int bn = blockIdx.x * BN, bm = blockIdx.y * BM;
  const int tid = threadIdx.x;
  const int tm = (tid >> 4) << 2;
  const int tn = (tid & 15) << 2;
  float acc[4][4] = {};
  for (int k0 = 0; k0 < C_DIM; k0 += BK) {
    for (int i = tid; i < BM * BK; i += 256) {
      int m = i >> 5, kk = i & 31;
      As[m][kk] = W[(size_t)(bm + m) * C_DIM + k0 + kk];
    }
    for (int i = tid; i < BK * BN; i += 256) {
      int kk = i >> 6, n = i & 63;
      Bs[kk][n] = Xb[(size_t)(k0 + kk) * N_SP + bn + n];
    }
    __syncthreads();
#pragma unroll
    for (int kk = 0; kk < BK; ++kk) {
      float a0 = As[tm + 0][kk], a1 = As[tm + 1][kk];
      float a2 = As[tm + 2][kk], a3 = As[tm + 3][kk];
      float4 bv = *(const float4*)&Bs[kk][tn];
      acc[0][0] += a0 * bv.x; acc[0][1] += a0 * bv.y; acc[0][2] += a0 * bv.z; acc[0][3] += a0 * bv.w;
      acc[1][0] += a1 * bv.x; acc[1][1] += a1 * bv.y; acc[1][2] += a1 * bv.z; acc[1][3] += a1 * bv.w;
      acc[2][0] += a2 * bv.x; acc[2][1] += a2 * bv.y; acc[2][2] += a2 * bv.z; acc[2][3] += a2 * bv.w;
      acc[3][0] += a3 * bv.x; acc[3][1] += a3 * bv.y; acc[3][2] += a3 * bv.z; acc[3][3] += a3 * bv.w;
    }
    __syncthreads();
  }
  float bia[4];
#pragma unroll
  for (int i = 0; i < 4; ++i) bia[i] = bias[bm + tm + i];

  if (MODE == 0) {
#pragma unroll
    for (int i = 0; i < 4; ++i) {
      int m = bm + tm + i;
#pragma unroll
      for (int j = 0; j < 4; ++j) {
        int n = bn + tn + j;
        float v = acc[i][j] + bia[i];
        if (R) v += R[boff + (size_t)m * N_SP + n];
        YF[boff + (size_t)m * N_SP + n] = v;
      }
    }
  } else if (MODE == 1) {
    // transposed bf16: YB[b][n][o], rows of C_DIM bf16
    ushort_t* Yb = YB + (size_t)blockIdx.z * N_SP * C_DIM;
#pragma unroll
    for (int j = 0; j < 4; ++j) {
      uint2 pk;
      pk.x = (unsigned)f2bf(acc[0][j] + bia[0]) | ((unsigned)f2bf(acc[1][j] + bia[1]) << 16);
      pk.y = (unsigned)f2bf(acc[2][j] + bia[2]) | ((unsigned)f2bf(acc[3][j] + bia[3]) << 16);
      *(uint2*)&Yb[(size_t)(bn + tn + j) * C_DIM + bm + tm] = pk;
    }
  } else {
    // natural bf16: YB[b][o][n]
    ushort_t* Yb = YB + (size_t)blockIdx.z * C_DIM * N_SP;
#pragma unroll
    for (int i = 0; i < 4; ++i) {
      uint2 pk;
      pk.x = (unsigned)f2bf(acc[i][0] + bia[i]) | ((unsigned)f2bf(acc[i][1] + bia[i]) << 16);
      pk.y = (unsigned)f2bf(acc[i][2] + bia[i]) | ((unsigned)f2bf(acc[i][3] + bia[i]) << 16);
      *(uint2*)&Yb[(size_t)(bm + tm + i) * N_SP + bn + tn] = pk;
    }
  }
}

// ---------------------------------------------------------------------------
// MFMA flash attention.
// qt, kt: bf16 [B][N][C] (c contiguous). vt: bf16 [B][C][N]. ao: fp32 [B][C][N].
// Grid (64, B): 64 queries/block. 4 waves, wave owns 16 queries. KT=64 keys/iter.
// S = mfma(Q_frag, K_frag): D row = query (lane>>4)*4+r, col = key lane&15.
// PV as O^T = mfma(V_frag, P_frag): D row = channel, col = query lane&15.
// LDS XOR-swizzle ((row&7)<<4 on bytes) both at staging-source and read.
// ---------------------------------------------------------------------------
__global__ __launch_bounds__(256) void attn_mfma(
    const ushort_t* __restrict__ qt, const ushort_t* __restrict__ kt,
    const ushort_t* __restrict__ vt, float* __restrict__ ao) {
  __shared__ __align__(16) ushort_t k_lds[64 * 256];   // [m][c]   32 KB
  __shared__ __align__(16) ushort_t v_lds[256 * 64];   // [c][m]   32 KB
  __shared__ __align__(16) ushort_t p_lds[4][16 * 64]; // per-wave [n'][m] 8 KB

  const int b  = blockIdx.y;
  const int q0 = blockIdx.x * 64;
  const int tid = threadIdx.x;
  const int wv = tid >> 6;
  const int ln = tid & 63;
  const int lo = ln & 15;
  const int g  = ln >> 4;

  const size_t plane = (size_t)b * N_SP * C_DIM;
  const ushort_t* qtb = qt + plane;
  const ushort_t* ktb = kt + plane;
  const ushort_t* vtb = vt + plane;

  // Q fragments in registers: A row = lane&15 (query), k = g*8 + j + 32*ks
  bf16x8 qf[8];
  {
    const ushort_t* qp = qtb + (size_t)(q0 + wv * 16 + lo) * C_DIM + g * 8;
#pragma unroll
    for (int ks = 0; ks < 8; ++ks) qf[ks] = *(const bf16x8*)(qp + ks * 32);
  }

  f32x4 o_acc[16];
#pragma unroll
  for (int i = 0; i < 16; ++i) o_acc[i] = (f32x4)(0.f);
  float m_run[4] = {-1e30f, -1e30f, -1e30f, -1e30f};
  float l_run[4] = {0.f, 0.f, 0.f, 0.f};

  for (int k0 = 0; k0 < N_SP; k0 += 64) {
    // ---- stage K tile rows [0,64) x [0,256) bf16: wave wv stages rows wv*16+..
    // linear LDS dest; source pre-swizzled so reads can XOR ((row&7)<<4).
#pragma unroll
    for (int i = 0; i < 8; ++i) {
      int m = wv * 16 + i * 2 + (ln >> 5);
      int sl = ln & 31;
      const ushort_t* src = ktb + (size_t)(k0 + m) * C_DIM + ((sl ^ (m & 7)) * 8);
      __builtin_amdgcn_global_load_lds(
          (const __attribute__((address_space(1))) unsigned int*)src,
          (__attribute__((address_space(3))) unsigned int*)&k_lds[(wv * 16 + i * 2) * 256],
          16, 0, 0);
    }
    // ---- stage V tile rows c in [0,256) x keys [k0,k0+64)
#pragma unroll
    for (int i = 0; i < 8; ++i) {
      int c = wv * 64 + i * 8 + (ln >> 3);
      int sl = ln & 7;
      const ushort_t* src = vtb + (size_t)c * N_SP + k0 + ((sl ^ (c & 7)) * 8);
      __builtin_amdgcn_global_load_lds(
          (const __attribute__((address_space(1))) unsigned int*)src,
          (__attribute__((address_space(3))) unsigned int*)&v_lds[(wv * 64 + i * 8) * 64],
          16, 0, 0);
    }
    __syncthreads();

    // ---- S = Q K^T : 4 col-tiles x 8 k-steps
    f32x4 sacc[4];
#pragma unroll
    for (int ct = 0; ct < 4; ++ct) sacc[ct] = (f32x4)(0.f);
#pragma unroll
    for (int ks = 0; ks < 8; ++ks) {
#pragma unroll
      for (int ct = 0; ct < 4; ++ct) {
        int m = lo + 16 * ct;
        bf16x8 kf = *(const bf16x8*)&k_lds[(m * 256 + g * 8 + ks * 32) ^ ((m & 7) << 3)];
        sacc[ct] = __builtin_amdgcn_mfma_f32_16x16x32_bf16(qf[ks], kf, sacc[ct], 0, 0, 0);
      }
    }

    // ---- online softmax (rows 4g+r live across the 16-lane group)
    const float scale = 0.0625f;
    float p[4][4], alpha[4];
#pragma unroll
    for (int r = 0; r < 4; ++r) {
      float a = fmaxf(fmaxf(sacc[0][r], sacc[1][r]), fmaxf(sacc[2][r], sacc[3][r]));
      a = fmaxf(a, __shfl_xor(a, 1));
      a = fmaxf(a, __shfl_xor(a, 2));
      a = fmaxf(a, __shfl_xor(a, 4));
      a = fmaxf(a, __shfl_xor(a, 8));
      float mn = fmaxf(m_run[r], a * scale);
      alpha[r] = __expf(m_run[r] - mn);
      m_run[r] = mn;
      float rs = 0.f;
#pragma unroll
      for (int ct = 0; ct < 4; ++ct) {
        float e = __expf(sacc[ct][r] * scale - mn);
        p[ct][r] = e; rs += e;
      }
      rs += __shfl_xor(rs, 1);
      rs += __shfl_xor(rs, 2);
      rs += __shfl_xor(rs, 4);
      rs += __shfl_xor(rs, 8);
      l_run[r] = l_run[r] * alpha[r] + rs;
    }

    // ---- P -> per-wave LDS (bf16), swizzled [n'][m] rows of 64
#pragma unroll
    for (int ct = 0; ct < 4; ++ct)
#pragma unroll
      for (int r = 0; r < 4; ++r) {
        int np = 4 * g + r;
        int mp = lo + 16 * ct;
        p_lds[wv][(np * 64 + mp) ^ ((np & 7) << 3)] = f2bf(p[ct][r]);
      }

    // ---- broadcast alpha to O^T layout (query = lane&15) and rescale O
    {
      int srcl = (lo >> 2) * 16;
      float a0 = __shfl(alpha[0], srcl);
      float a1 = __shfl(alpha[1], srcl);
      float a2 = __shfl(alpha[2], srcl);
      float a3 = __shfl(alpha[3], srcl);
      int rr = lo & 3;
      float alphaB = rr == 0 ? a0 : rr == 1 ? a1 : (rr == 2 ? a2 : a3);
      if (!__all(alphaB == 1.f)) {
#pragma unroll
        for (int i = 0; i < 16; ++i) o_acc[i] *= alphaB;
      }
    }

    // ---- PV: O^T = V^T P^T ; A = V frag (row=c), B = P frag (col=query)
#pragma unroll
    for (int ks2 = 0; ks2 < 2; ++ks2) {
      bf16x8 pf = *(const bf16x8*)&p_lds[wv][(lo * 64 + g * 8 + ks2 * 32) ^ ((lo & 7) << 3)];
#pragma unroll
      for (int ot = 0; ot < 16; ++ot) {
        int c = ot * 16 + lo;
        bf16x8 vf = *(const bf16x8*)&v_lds[(c * 64 + g * 8 + ks2 * 32) ^ ((c & 7) << 3)];
        o_acc[ot] = __builtin_amdgcn_mfma_f32_16x16x32_bf16(vf, pf, o_acc[ot], 0, 0, 0);
      }
    }
    __syncthreads();
  }

  // ---- epilogue: divide by l (per query = lane&15), store ao fp32 [c][n]
  {
    int srcl = (lo >> 2) * 16;
    float L0 = __shfl(l_run[0], srcl);
    float L1 = __shfl(l_run[1], srcl);
    float L2 = __shfl(l_run[2], srcl);
    float L3 = __shfl(l_run[3], srcl);
    int rr = lo & 3;
    float lB = rr == 0 ? L0 : rr == 1 ? L1 : (rr == 2 ? L2 : L3);
    float invB = 1.f / lB;
    float* aob = ao + (size_t)b * C_DIM * N_SP;
    const int ncol = q0 + wv * 16 + lo;
#pragma unroll
    for (int ot = 0; ot < 16; ++ot)
#pragma unroll
      for (int r = 0; r < 4; ++r) {
        int c = ot * 16 + 4 * g + r;
        aob[(size_t)c * N_SP + ncol] = o_acc[ot][r] * invB;
      }
  }
}

// ---------------------------------------------------------------------------
extern "C" void kernel_launch(void* const* d_in, const int* in_sizes, int n_in,
                              void* d_out, int out_size, void* d_ws, size_t ws_size,
                              hipStream_t stream) {
  const float* x   = (const float*)d_in[0];
  const float* gnw = (const float*)d_in[1];
  const float* gnb = (const float*)d_in[2];
  const float* wq  = (const float*)d_in[3];
  const float* bq  = (const float*)d_in[4];
  const float* wk  = (const float*)d_in[5];
  const float* bk  = (const float*)d_in[6];
  const float* wv  = (const float*)d_in[7];
  const float* bv  = (const float*)d_in[8];
  const float* wp  = (const float*)d_in[9];
  const float* bp  = (const float*)d_in[10];
  float* out = (float*)d_out;

  const size_t CN = (size_t)C_DIM * N_SP;
  // ws: h fp32 | ao fp32 | qt bf16 | kt bf16 | vt bf16  = 8+8+4+4+4 = 28 MB
  float* h  = (float*)d_ws;
  float* ab = h + (size_t)B_DIM * CN;
  ushort_t* qtw = (ushort_t*)(ab + (size_t)B_DIM * CN);
  ushort_t* ktw = qtw + (size_t)B_DIM * CN;
  ushort_t* vtw = ktw + (size_t)B_DIM * CN;

  gn_kernel<<<dim3(B_DIM * 32), dim3(256), 0, stream>>>(x, gnw, gnb, h);

  dim3 gg(N_SP / BN, C_DIM / BM, B_DIM);
  gemm_kernel<1><<<gg, dim3(256), 0, stream>>>(wq, bq, h, nullptr, qtw, nullptr);
  gemm_kernel<1><<<gg, dim3(256), 0, stream>>>(wk, bk, h, nullptr, ktw, nullptr);
  gemm_kernel<2><<<gg, dim3(256), 0, stream>>>(wv, bv, h, nullptr, vtw, nullptr);

  attn_mfma<<<dim3(N_SP / 64, B_DIM), dim3(256), 0, stream>>>(qtw, ktw, vtw, ab);

  gemm_kernel<0><<<gg, dim3(256), 0, stream>>>(wp, bp, ab, out, nullptr, x);
}

// Round 4
// 211.437 us; speedup vs baseline: 6.9043x; 1.8312x over previous
//
#include <hip/hip_runtime.h>

#define C_DIM 256
#define N_SP  4096
#define B_DIM 2
#define CPG   8
#define EPS_GN 1e-5f
#define CN ((size_t)C_DIM * N_SP)

typedef unsigned short ushort_t;
typedef unsigned int uint_t;
typedef __attribute__((ext_vector_type(4))) float f32x4;
typedef __attribute__((ext_vector_type(4))) unsigned int u32x4;
typedef __attribute__((ext_vector_type(8))) short bf16x8;

__device__ inline ushort_t f2bf(float f) {
  union { float f; unsigned u; } v; v.f = f;
  unsigned r = v.u + 0x7FFF + ((v.u >> 16) & 1);   // RNE
  return (ushort_t)(r >> 16);
}
__device__ inline uint_t pkbf(float a, float b) {
  return (uint_t)f2bf(a) | ((uint_t)f2bf(b) << 16);
}
__device__ inline float bf2f(uint_t u) {
  union { uint_t u; float f; } v; v.u = u << 16; return v.f;
}

#define GLOAD16(src, dst) __builtin_amdgcn_global_load_lds( \
    (const __attribute__((address_space(1))) unsigned int*)(src), \
    (__attribute__((address_space(3))) unsigned int*)(dst), 16, 0, 0)

// ---------------------------------------------------------------------------
// Weight conversion: 4 x (256x256) fp32 -> bf16, concatenated.
// ---------------------------------------------------------------------------
__global__ __launch_bounds__(256) void wcvt_kernel(const float* __restrict__ wq,
    const float* __restrict__ wk, const float* __restrict__ wv,
    const float* __restrict__ wp, ushort_t* __restrict__ o) {
  int gid = blockIdx.x * 256 + threadIdx.x;
  int i4 = gid * 4;
  const float* s = (i4 < 65536) ? wq : (i4 < 131072) ? wk : (i4 < 196608) ? wv : wp;
  int off = i4 & 65535;
  float4 v = *(const float4*)(s + off);
  uint2 p; p.x = pkbf(v.x, v.y); p.y = pkbf(v.z, v.w);
  *(uint2*)&o[i4] = p;
}

// ---------------------------------------------------------------------------
// GroupNorm -> hT bf16 [B][N][C] (transposed, k-contiguous for MFMA GEMMs).
// ---------------------------------------------------------------------------
__global__ __launch_bounds__(256) void gn_kernel(const float* __restrict__ x,
    const float* __restrict__ w, const float* __restrict__ bgn,
    ushort_t* __restrict__ hT) {
  const int bg = blockIdx.x;
  const int b = bg >> 5, g = bg & 31;
  const size_t base = ((size_t)b * C_DIM + (size_t)g * CPG) * N_SP;
  const float* xp = x + base;
  const int tid = threadIdx.x;
  const int TOT = CPG * N_SP;
  float s = 0.f, ss = 0.f;
  for (int i = tid; i < TOT; i += 256) {
    float v = xp[i];
    s += v; ss += v * v;
  }
#pragma unroll
  for (int off = 32; off > 0; off >>= 1) {
    s  += __shfl_down(s, off);
    ss += __shfl_down(ss, off);
  }
  __shared__ float rs[4], rss[4];
  __shared__ float smean, srstd;
  const int wvi = tid >> 6, lnn = tid & 63;
  if (lnn == 0) { rs[wvi] = s; rss[wvi] = ss; }
  __syncthreads();
  if (tid == 0) {
    float S  = rs[0] + rs[1] + rs[2] + rs[3];
    float SS = rss[0] + rss[1] + rss[2] + rss[3];
    float mean = S / (float)TOT;
    float var  = SS / (float)TOT - mean * mean;
    smean = mean;
    srstd = rsqrtf(var + EPS_GN);
  }
  __syncthreads();
  const float mean = smean, rstd = srstd;
  float sc[8], sh[8];
#pragma unroll
  for (int c = 0; c < 8; ++c) {
    sc[c] = w[g * 8 + c] * rstd;
    sh[c] = bgn[g * 8 + c] - mean * sc[c];
  }
  __shared__ float tile[8][256];
  ushort_t* hb = hT + (size_t)b * N_SP * C_DIM + g * 8;
  for (int n0 = 0; n0 < N_SP; n0 += 256) {
    for (int i = tid; i < 8 * 256; i += 256) {
      int cc = i >> 8, n = i & 255;
      tile[cc][n] = xp[(size_t)cc * N_SP + n0 + n];
    }
    __syncthreads();
    u32x4 pk4;
#pragma unroll
    for (int p = 0; p < 4; ++p)
      pk4[p] = pkbf(tile[2 * p][tid] * sc[2 * p] + sh[2 * p],
                    tile[2 * p + 1][tid] * sc[2 * p + 1] + sh[2 * p + 1]);
    *(u32x4*)&hb[(size_t)(n0 + tid) * C_DIM] = pk4;
    __syncthreads();
  }
}

// ---------------------------------------------------------------------------
// MFMA GEMM over k-contiguous bf16 operands A[M][256], B[N][256]:
//   D[m][n] = sum_k A[m][k] B[n][k]  (+bias, +residual)
// MODE 0: out bf16, bias indexed by col (QK: out[n][o] + b[o])
// MODE 1: out bf16, bias indexed by row (V:  out[o][n] + b[o])
// MODE 2: out fp32, bias by row + residual R (proj: out[o][n] + b[o] + x)
// ---------------------------------------------------------------------------
template <int MODE>
__global__ __launch_bounds__(256) void mgemm(
    const ushort_t* __restrict__ A, const ushort_t* __restrict__ Bm,
    const float* __restrict__ bias, ushort_t* __restrict__ outB,
    float* __restrict__ outF, const float* __restrict__ R,
    int aStride, int bStride, int ldo) {
  __shared__ __align__(16) ushort_t a_lds[128 * 64];
  __shared__ __align__(16) ushort_t b_lds[128 * 64];
  const int bz = blockIdx.z;
  const ushort_t* Ab = A + (size_t)bz * aStride;
  const ushort_t* Bb = Bm + (size_t)bz * bStride;
  const int bm = blockIdx.y * 128, bn = blockIdx.x * 128;
  const int tid = threadIdx.x, wv = tid >> 6, ln = tid & 63;
  const int lo = ln & 15, g = ln >> 4;
  const int wr = wv >> 1, wc = wv & 1;

  f32x4 acc[4][4];
#pragma unroll
  for (int i = 0; i < 4; ++i)
#pragma unroll
    for (int j = 0; j < 4; ++j) acc[i][j] = (f32x4)(0.f);

  float bcol[4];
  float brow = 0.f;
  if (MODE == 0) {
#pragma unroll
    for (int ct = 0; ct < 4; ++ct) bcol[ct] = bias[bn + wc * 64 + ct * 16 + lo];
  } else {
    brow = bias[bm + wr * 64 + ln];
  }

  for (int k0 = 0; k0 < C_DIM; k0 += 64) {
#pragma unroll
    for (int i = 0; i < 4; ++i) {
      int r0 = wv * 32 + i * 8;
      int row = r0 + (ln >> 3);
      GLOAD16(Ab + (size_t)(bm + row) * C_DIM + k0 + (((ln & 7) ^ (row & 7)) << 3),
              &a_lds[r0 * 64]);
      GLOAD16(Bb + (size_t)(bn + row) * C_DIM + k0 + (((ln & 7) ^ (row & 7)) << 3),
              &b_lds[r0 * 64]);
    }
    __syncthreads();
    bf16x8 af[4][2], bfr[4][2];
#pragma unroll
    for (int rt = 0; rt < 4; ++rt)
#pragma unroll
      for (int ks = 0; ks < 2; ++ks) {
        int row = wr * 64 + rt * 16 + lo;
        af[rt][ks] = *(const bf16x8*)&a_lds[row * 64 + (((ks * 4 + g) ^ (row & 7)) << 3)];
      }
#pragma unroll
    for (int ct = 0; ct < 4; ++ct)
#pragma unroll
      for (int ks = 0; ks < 2; ++ks) {
        int col = wc * 64 + ct * 16 + lo;
        bfr[ct][ks] = *(const bf16x8*)&b_lds[col * 64 + (((ks * 4 + g) ^ (col & 7)) << 3)];
      }
#pragma unroll
    for (int ks = 0; ks < 2; ++ks)
#pragma unroll
      for (int rt = 0; rt < 4; ++rt)
#pragma unroll
        for (int ct = 0; ct < 4; ++ct)
          acc[rt][ct] = __builtin_amdgcn_mfma_f32_16x16x32_bf16(af[rt][ks], bfr[ct][ks], acc[rt][ct], 0, 0, 0);
    __syncthreads();
  }

  // Epilogue: per-wave 8KB LDS transpose (64 rows x 32 cols per phase).
  // Store at (lcol ^ swz); read back at ((4cb) ^ swz) which yields columns
  // 4cb..4cb+3 directly -> buf[cb]. (R3 bug: double-applied the inverse.)
  float* wbase = (wv < 2 ? (float*)a_lds : (float*)b_lds) + (wv & 1) * 2048;
  const int grow = bm + wr * 64 + ln;
#pragma unroll
  for (int p = 0; p < 2; ++p) {
#pragma unroll
    for (int rt = 0; rt < 4; ++rt)
#pragma unroll
      for (int cth = 0; cth < 2; ++cth) {
        int ct = 2 * p + cth;
#pragma unroll
        for (int r = 0; r < 4; ++r) {
          int lrow = rt * 16 + 4 * g + r;
          int lcol = cth * 16 + lo;
          float v = acc[rt][ct][r];
          if (MODE == 0) v += bcol[ct];
          wbase[lrow * 32 + (lcol ^ ((lrow & 7) << 2))] = v;
        }
      }
    f32x4 buf[8];
#pragma unroll
    for (int cb = 0; cb < 8; ++cb) {
      int off = (4 * cb) ^ ((ln & 7) << 2);
      f32x4 t = *(const f32x4*)&wbase[ln * 32 + off];
      buf[cb] = t;
    }
    const size_t obase = (size_t)grow * ldo + bn + wc * 64 + p * 32;
    if (MODE == 2) {
      const float* Rb = R + (size_t)bz * CN + obase;
      float* ob = outF + (size_t)bz * CN + obase;
#pragma unroll
      for (int cb = 0; cb < 8; ++cb) {
        f32x4 t = buf[cb];
        f32x4 rv = *(const f32x4*)&Rb[4 * cb];
#pragma unroll
        for (int j = 0; j < 4; ++j) t[j] += brow + rv[j];
        *(f32x4*)&ob[4 * cb] = t;
      }
    } else {
      float badd = (MODE == 0) ? 0.f : brow;
      ushort_t* ob = outB + (size_t)bz * CN + obase;
      uint_t wpk[16];
#pragma unroll
      for (int k = 0; k < 16; ++k)
        wpk[k] = pkbf(buf[k >> 1][(k & 1) * 2] + badd, buf[k >> 1][(k & 1) * 2 + 1] + badd);
#pragma unroll
      for (int sidx = 0; sidx < 4; ++sidx) {
        u32x4 t;
        t[0] = wpk[4 * sidx]; t[1] = wpk[4 * sidx + 1];
        t[2] = wpk[4 * sidx + 2]; t[3] = wpk[4 * sidx + 3];
        *(u32x4*)&ob[sidx * 8] = t;
      }
    }
    __syncthreads();
  }
}

// ---------------------------------------------------------------------------
// MFMA flash attention, split-K over 4 key-ranges of 1024.
// ---------------------------------------------------------------------------
__global__ __launch_bounds__(256) void attn_mfma(
    const ushort_t* __restrict__ qt, const ushort_t* __restrict__ kt,
    const ushort_t* __restrict__ vt, ushort_t* __restrict__ pO,
    float* __restrict__ pml) {
  __shared__ __align__(16) ushort_t k_lds[64 * 256];   // 32 KB
  __shared__ __align__(16) ushort_t v_lds[256 * 64];   // 32 KB
  __shared__ __align__(16) ushort_t p_lds[4][16 * 64]; // 8 KB

  const int ksplit = blockIdx.y;
  const int b  = blockIdx.z;
  const int q0 = blockIdx.x * 64;
  const int tid = threadIdx.x;
  const int wv = tid >> 6;
  const int ln = tid & 63;
  const int lo = ln & 15;
  const int g  = ln >> 4;

  const size_t plane = (size_t)b * N_SP * C_DIM;
  const ushort_t* qtb = qt + plane;
  const ushort_t* ktb = kt + plane;
  const ushort_t* vtb = vt + plane;

  bf16x8 qf[8];
  {
    const ushort_t* qp = qtb + (size_t)(q0 + wv * 16 + lo) * C_DIM + g * 8;
#pragma unroll
    for (int ks = 0; ks < 8; ++ks) qf[ks] = *(const bf16x8*)(qp + ks * 32);
  }

  f32x4 o_acc[16];
#pragma unroll
  for (int i = 0; i < 16; ++i) o_acc[i] = (f32x4)(0.f);
  float m_run[4] = {-1e30f, -1e30f, -1e30f, -1e30f};
  float l_run[4] = {0.f, 0.f, 0.f, 0.f};

  for (int t = 0; t < 16; ++t) {
    const int k0 = ksplit * 1024 + t * 64;
#pragma unroll
    for (int i = 0; i < 8; ++i) {
      int m = wv * 16 + i * 2 + (ln >> 5);
      int sl = ln & 31;
      const ushort_t* src = ktb + (size_t)(k0 + m) * C_DIM + ((sl ^ (m & 7)) * 8);
      GLOAD16(src, &k_lds[(wv * 16 + i * 2) * 256]);
    }
#pragma unroll
    for (int i = 0; i < 8; ++i) {
      int c = wv * 64 + i * 8 + (ln >> 3);
      int sl = ln & 7;
      const ushort_t* src = vtb + (size_t)c * N_SP + k0 + ((sl ^ (c & 7)) * 8);
      GLOAD16(src, &v_lds[(wv * 64 + i * 8) * 64]);
    }
    __syncthreads();

    f32x4 sacc[4];
#pragma unroll
    for (int ct = 0; ct < 4; ++ct) sacc[ct] = (f32x4)(0.f);
#pragma unroll
    for (int ks = 0; ks < 8; ++ks) {
#pragma unroll
      for (int ct = 0; ct < 4; ++ct) {
        int m = lo + 16 * ct;
        bf16x8 kf = *(const bf16x8*)&k_lds[(m * 256 + g * 8 + ks * 32) ^ ((m & 7) << 3)];
        sacc[ct] = __builtin_amdgcn_mfma_f32_16x16x32_bf16(qf[ks], kf, sacc[ct], 0, 0, 0);
      }
    }

    const float scale = 0.0625f;
    float p[4][4], alpha[4];
#pragma unroll
    for (int r = 0; r < 4; ++r) {
      float a = fmaxf(fmaxf(sacc[0][r], sacc[1][r]), fmaxf(sacc[2][r], sacc[3][r]));
      a = fmaxf(a, __shfl_xor(a, 1));
      a = fmaxf(a, __shfl_xor(a, 2));
      a = fmaxf(a, __shfl_xor(a, 4));
      a = fmaxf(a, __shfl_xor(a, 8));
      float mn = fmaxf(m_run[r], a * scale);
      alpha[r] = __expf(m_run[r] - mn);
      m_run[r] = mn;
      float rsum = 0.f;
#pragma unroll
      for (int ct = 0; ct < 4; ++ct) {
        float e = __expf(sacc[ct][r] * scale - mn);
        p[ct][r] = e; rsum += e;
      }
      rsum += __shfl_xor(rsum, 1);
      rsum += __shfl_xor(rsum, 2);
      rsum += __shfl_xor(rsum, 4);
      rsum += __shfl_xor(rsum, 8);
      l_run[r] = l_run[r] * alpha[r] + rsum;
    }

#pragma unroll
    for (int ct = 0; ct < 4; ++ct)
#pragma unroll
      for (int r = 0; r < 4; ++r) {
        int np = 4 * g + r;
        int mp = lo + 16 * ct;
        p_lds[wv][(np * 64 + mp) ^ ((np & 7) << 3)] = f2bf(p[ct][r]);
      }

    {
      int srcl = (lo >> 2) * 16;
      float a0 = __shfl(alpha[0], srcl);
      float a1 = __shfl(alpha[1], srcl);
      float a2 = __shfl(alpha[2], srcl);
      float a3 = __shfl(alpha[3], srcl);
      int rr = lo & 3;
      float alphaB = rr == 0 ? a0 : rr == 1 ? a1 : (rr == 2 ? a2 : a3);
      if (!__all(alphaB == 1.f)) {
#pragma unroll
        for (int i = 0; i < 16; ++i) o_acc[i] *= alphaB;
      }
    }

#pragma unroll
    for (int ks2 = 0; ks2 < 2; ++ks2) {
      bf16x8 pf = *(const bf16x8*)&p_lds[wv][(lo * 64 + g * 8 + ks2 * 32) ^ ((lo & 7) << 3)];
#pragma unroll
      for (int ot = 0; ot < 16; ++ot) {
        int c = ot * 16 + lo;
        bf16x8 vf = *(const bf16x8*)&v_lds[(c * 64 + g * 8 + ks2 * 32) ^ ((c & 7) << 3)];
        o_acc[ot] = __builtin_amdgcn_mfma_f32_16x16x32_bf16(vf, pf, o_acc[ot], 0, 0, 0);
      }
    }
    __syncthreads();
  }

  // Epilogue: transpose O^T (c,q) -> rows n with c contiguous, store bf16 partials.
  uint_t* tbase = (uint_t*)&k_lds[0] + wv * 2048;   // 8KB per wave
#pragma unroll
  for (int ot = 0; ot < 16; ++ot)
#pragma unroll
    for (int p2 = 0; p2 < 2; ++p2) {
      uint_t w32 = pkbf(o_acc[ot][2 * p2], o_acc[ot][2 * p2 + 1]);
      int word = ot * 8 + 2 * g + p2;
      tbase[lo * 128 + (word ^ ((lo & 7) << 2))] = w32;
    }
  {
    const int q = ln >> 2, quarter = ln & 3;
    const size_t row32 = (((size_t)(ksplit * B_DIM + b) * N_SP) + q0 + wv * 16 + q) * (C_DIM / 2);
    uint_t* pO32 = (uint_t*)pO;
#pragma unroll
    for (int cb = 0; cb < 8; ++cb) {
      int off = (quarter * 32 + 4 * cb) ^ ((q & 7) << 2);
      u32x4 tv = *(const u32x4*)&tbase[q * 128 + off];
      *(u32x4*)&pO32[row32 + quarter * 32 + 4 * cb] = tv;
    }
  }
  if (lo == 0) {
#pragma unroll
    for (int r = 0; r < 4; ++r) {
      int qg = q0 + wv * 16 + 4 * g + r;
      size_t mi = (((size_t)(ksplit * B_DIM + b) * N_SP) + qg) * 2;
      pml[mi] = m_run[r];
      pml[mi + 1] = l_run[r];
    }
  }
}

// ---------------------------------------------------------------------------
// Merge 4 split-K partials -> aoT bf16 [B][N][C].
// ---------------------------------------------------------------------------
__global__ __launch_bounds__(256) void merge_kernel(const ushort_t* __restrict__ pO,
    const float* __restrict__ pml, ushort_t* __restrict__ aoT) {
  const int b = blockIdx.y;
  const int n = blockIdx.x * 16 + (threadIdx.x >> 4);
  const int cg = threadIdx.x & 15;
  float mi[4], li[4];
#pragma unroll
  for (int i = 0; i < 4; ++i) {
    size_t o = (((size_t)(i * B_DIM + b) * N_SP) + n) * 2;
    mi[i] = pml[o]; li[i] = pml[o + 1];
  }
  float ms = fmaxf(fmaxf(mi[0], mi[1]), fmaxf(mi[2], mi[3]));
  float wsum = 0.f, wi[4];
#pragma unroll
  for (int i = 0; i < 4; ++i) { wi[i] = __expf(mi[i] - ms); wsum += wi[i] * li[i]; }
  float inv = 1.f / wsum;
  float acc[16] = {};
#pragma unroll
  for (int i = 0; i < 4; ++i) {
    const ushort_t* p = pO + (((size_t)(i * B_DIM + b) * N_SP) + n) * C_DIM + cg * 16;
    u32x4 a = *(const u32x4*)p;
    u32x4 c2 = *(const u32x4*)(p + 8);
#pragma unroll
    for (int j = 0; j < 4; ++j) {
      acc[2 * j]     += wi[i] * bf2f(a[j] & 0xffffu);
      acc[2 * j + 1] += wi[i] * bf2f(a[j] >> 16);
      acc[8 + 2 * j]     += wi[i] * bf2f(c2[j] & 0xffffu);
      acc[8 + 2 * j + 1] += wi[i] * bf2f(c2[j] >> 16);
    }
  }
  ushort_t* ob = aoT + ((size_t)b * N_SP + n) * C_DIM + cg * 16;
  u32x4 o0, o1;
#pragma unroll
  for (int k = 0; k < 4; ++k) o0[k] = pkbf(acc[2 * k] * inv, acc[2 * k + 1] * inv);
#pragma unroll
  for (int k = 0; k < 4; ++k) o1[k] = pkbf(acc[8 + 2 * k] * inv, acc[8 + 2 * k + 1] * inv);
  *(u32x4*)&ob[0] = o0;
  *(u32x4*)&ob[8] = o1;
}

// ---------------------------------------------------------------------------
extern "C" void kernel_launch(void* const* d_in, const int* in_sizes, int n_in,
                              void* d_out, int out_size, void* d_ws, size_t ws_size,
                              hipStream_t stream) {
  const float* x   = (const float*)d_in[0];
  const float* gnw = (const float*)d_in[1];
  const float* gnb = (const float*)d_in[2];
  const float* wq  = (const float*)d_in[3];
  const float* bq  = (const float*)d_in[4];
  const float* wk  = (const float*)d_in[5];
  const float* bk  = (const float*)d_in[6];
  const float* wv  = (const float*)d_in[7];
  const float* bv  = (const float*)d_in[8];
  const float* wp  = (const float*)d_in[9];
  const float* bp  = (const float*)d_in[10];
  float* out = (float*)d_out;

  char* w8 = (char*)d_ws;
  ushort_t* hT  = (ushort_t*)w8;
  ushort_t* wb  = (ushort_t*)(w8 + ((size_t)4 << 20));
  ushort_t* qT  = (ushort_t*)(w8 + ((size_t)4 << 20) + ((size_t)1 << 19));
  ushort_t* kT  = qT + B_DIM * CN;
  ushort_t* vN  = kT + B_DIM * CN;
  ushort_t* aoT = vN + B_DIM * CN;
  float*    pml = (float*)(aoT + B_DIM * CN);
  ushort_t* pO  = (ushort_t*)((char*)pml + (size_t)4 * B_DIM * N_SP * 2 * 4);

  ushort_t* wqb = wb;
  ushort_t* wkb = wb + 65536;
  ushort_t* wvb = wb + 131072;
  ushort_t* wpb = wb + 196608;

  wcvt_kernel<<<dim3(256), dim3(256), 0, stream>>>(wq, wk, wv, wp, wb);
  gn_kernel<<<dim3(B_DIM * 32), dim3(256), 0, stream>>>(x, gnw, gnb, hT);

  mgemm<0><<<dim3(2, 32, B_DIM), dim3(256), 0, stream>>>(hT, wqb, bq, qT, nullptr, nullptr, (int)CN, 0, C_DIM);
  mgemm<0><<<dim3(2, 32, B_DIM), dim3(256), 0, stream>>>(hT, wkb, bk, kT, nullptr, nullptr, (int)CN, 0, C_DIM);
  mgemm<1><<<dim3(32, 2, B_DIM), dim3(256), 0, stream>>>(wvb, hT, bv, vN, nullptr, nullptr, 0, (int)CN, N_SP);

  attn_mfma<<<dim3(64, 4, B_DIM), dim3(256), 0, stream>>>(qT, kT, vN, pO, pml);
  merge_kernel<<<dim3(256, B_DIM), dim3(256), 0, stream>>>(pO, pml, aoT);

  mgemm<2><<<dim3(32, 2, B_DIM), dim3(256), 0, stream>>>(wpb, aoT, bp, nullptr, out, x, 0, (int)CN, N_SP);
}

// Round 5
// 210.096 us; speedup vs baseline: 6.9484x; 1.0064x over previous
//
#include <hip/hip_runtime.h>

#define C_DIM 256
#define N_SP  4096
#define B_DIM 2
#define CPG   8
#define EPS_GN 1e-5f
#define CN ((size_t)C_DIM * N_SP)

typedef unsigned short ushort_t;
typedef unsigned int uint_t;
typedef __attribute__((ext_vector_type(4))) float f32x4;
typedef __attribute__((ext_vector_type(4))) unsigned int u32x4;
typedef __attribute__((ext_vector_type(8))) short bf16x8;

__device__ inline ushort_t f2bf(float f) {
  union { float f; unsigned u; } v; v.f = f;
  unsigned r = v.u + 0x7FFF + ((v.u >> 16) & 1);   // RNE
  return (ushort_t)(r >> 16);
}
__device__ inline uint_t pkbf(float a, float b) {
  return (uint_t)f2bf(a) | ((uint_t)f2bf(b) << 16);
}
__device__ inline float bf2f(uint_t u) {
  union { uint_t u; float f; } v; v.u = u << 16; return v.f;
}

#define GLOAD16(src, dst) __builtin_amdgcn_global_load_lds( \
    (const __attribute__((address_space(1))) unsigned int*)(src), \
    (__attribute__((address_space(3))) unsigned int*)(dst), 16, 0, 0)

// ---------------------------------------------------------------------------
// Weight conversion: 4 x (256x256) fp32 -> bf16 concatenated [wq;wk;wv;wp].
// ---------------------------------------------------------------------------
__global__ __launch_bounds__(256) void wcvt_kernel(const float* __restrict__ wq,
    const float* __restrict__ wk, const float* __restrict__ wv,
    const float* __restrict__ wp, ushort_t* __restrict__ o) {
  int gid = blockIdx.x * 256 + threadIdx.x;
  int i4 = gid * 4;
  const float* s = (i4 < 65536) ? wq : (i4 < 131072) ? wk : (i4 < 196608) ? wv : wp;
  int off = i4 & 65535;
  float4 v = *(const float4*)(s + off);
  uint2 p; p.x = pkbf(v.x, v.y); p.y = pkbf(v.z, v.w);
  *(uint2*)&o[i4] = p;
}

// ---------------------------------------------------------------------------
// GroupNorm stats: grid (64, 4) -> partial (sum, sumsq) per (bg, quarter).
// ---------------------------------------------------------------------------
__global__ __launch_bounds__(256) void gn_stats(const float* __restrict__ x,
    float* __restrict__ part) {
  const int bg = blockIdx.x, sub = blockIdx.y;
  const float* xp = x + (size_t)bg * CPG * N_SP + (size_t)sub * (CPG * N_SP / 4);
  const int tid = threadIdx.x;
  float s = 0.f, ss = 0.f;
  for (int i = tid; i < CPG * N_SP / 4; i += 256) {
    float v = xp[i];
    s += v; ss += v * v;
  }
#pragma unroll
  for (int off = 32; off > 0; off >>= 1) {
    s  += __shfl_down(s, off);
    ss += __shfl_down(ss, off);
  }
  __shared__ float rs[4], rss[4];
  const int wv = tid >> 6, ln = tid & 63;
  if (ln == 0) { rs[wv] = s; rss[wv] = ss; }
  __syncthreads();
  if (tid == 0) {
    part[(bg * 4 + sub) * 2]     = rs[0] + rs[1] + rs[2] + rs[3];
    part[(bg * 4 + sub) * 2 + 1] = rss[0] + rss[1] + rss[2] + rss[3];
  }
}

// ---------------------------------------------------------------------------
// GroupNorm apply -> hT bf16 [B][N][C]. grid (64, 16): (bg, n-chunk of 256).
// ---------------------------------------------------------------------------
__global__ __launch_bounds__(256) void gn_apply(const float* __restrict__ x,
    const float* __restrict__ part, const float* __restrict__ w,
    const float* __restrict__ bgn, ushort_t* __restrict__ hT) {
  const int bg = blockIdx.x;
  const int b = bg >> 5, g = bg & 31;
  const int n0 = blockIdx.y * 256;
  const int tid = threadIdx.x;
  float S = 0.f, SS = 0.f;
#pragma unroll
  for (int i = 0; i < 4; ++i) {
    S  += part[(bg * 4 + i) * 2];
    SS += part[(bg * 4 + i) * 2 + 1];
  }
  const float mean = S / (float)(CPG * N_SP);
  const float var  = SS / (float)(CPG * N_SP) - mean * mean;
  const float rstd = rsqrtf(var + EPS_GN);
  float sc[8], sh[8];
#pragma unroll
  for (int c = 0; c < 8; ++c) {
    sc[c] = w[g * 8 + c] * rstd;
    sh[c] = bgn[g * 8 + c] - mean * sc[c];
  }
  __shared__ float tile[8][256];
  const float* xp = x + ((size_t)b * C_DIM + (size_t)g * CPG) * N_SP;
  for (int i = tid; i < 8 * 256; i += 256) {
    int cc = i >> 8, n = i & 255;
    tile[cc][n] = xp[(size_t)cc * N_SP + n0 + n];
  }
  __syncthreads();
  u32x4 pk4;
#pragma unroll
  for (int p = 0; p < 4; ++p)
    pk4[p] = pkbf(tile[2 * p][tid] * sc[2 * p] + sh[2 * p],
                  tile[2 * p + 1][tid] * sc[2 * p + 1] + sh[2 * p + 1]);
  *(u32x4*)&hT[((size_t)b * N_SP + n0 + tid) * C_DIM + g * 8] = pk4;
}

// ---------------------------------------------------------------------------
// MFMA GEMM, k-contiguous bf16 operands A[M][256], B[N][256]:
//   D[m][n] = sum_k A[m][k] B[n][k]  (+bias, +residual)
// MODE 0: out bf16 [m][n]-major rows ldo, bias by col with q/k split at 256
// MODE 1: out bf16, bias by row (V)
// MODE 2: out fp32, bias by row + residual (proj)
// ---------------------------------------------------------------------------
template <int MODE>
__global__ __launch_bounds__(256) void mgemm(
    const ushort_t* __restrict__ A, const ushort_t* __restrict__ Bm,
    const float* __restrict__ biasA, const float* __restrict__ biasB,
    ushort_t* __restrict__ outB, float* __restrict__ outF,
    const float* __restrict__ R, int aStride, int bStride, int ldo,
    size_t obStride) {
  __shared__ __align__(16) ushort_t a_lds[128 * 64];
  __shared__ __align__(16) ushort_t b_lds[128 * 64];
  const int bz = blockIdx.z;
  const ushort_t* Ab = A + (size_t)bz * aStride;
  const ushort_t* Bb = Bm + (size_t)bz * bStride;
  const int bm = blockIdx.y * 128, bn = blockIdx.x * 128;
  const int tid = threadIdx.x, wv = tid >> 6, ln = tid & 63;
  const int lo = ln & 15, g = ln >> 4;
  const int wr = wv >> 1, wc = wv & 1;

  f32x4 acc[4][4];
#pragma unroll
  for (int i = 0; i < 4; ++i)
#pragma unroll
    for (int j = 0; j < 4; ++j) acc[i][j] = (f32x4)(0.f);

  float bcol[4];
  float brow = 0.f;
  if (MODE == 0) {
#pragma unroll
    for (int ct = 0; ct < 4; ++ct) {
      int col = bn + wc * 64 + ct * 16 + lo;
      bcol[ct] = (col < 256) ? biasA[col] : biasB[col - 256];
    }
  } else {
    brow = biasA[bm + wr * 64 + ln];
  }

  for (int k0 = 0; k0 < C_DIM; k0 += 64) {
#pragma unroll
    for (int i = 0; i < 4; ++i) {
      int r0 = wv * 32 + i * 8;
      int row = r0 + (ln >> 3);
      GLOAD16(Ab + (size_t)(bm + row) * C_DIM + k0 + (((ln & 7) ^ (row & 7)) << 3),
              &a_lds[r0 * 64]);
      GLOAD16(Bb + (size_t)(bn + row) * C_DIM + k0 + (((ln & 7) ^ (row & 7)) << 3),
              &b_lds[r0 * 64]);
    }
    __syncthreads();
    bf16x8 af[4][2], bfr[4][2];
#pragma unroll
    for (int rt = 0; rt < 4; ++rt)
#pragma unroll
      for (int ks = 0; ks < 2; ++ks) {
        int row = wr * 64 + rt * 16 + lo;
        af[rt][ks] = *(const bf16x8*)&a_lds[row * 64 + (((ks * 4 + g) ^ (row & 7)) << 3)];
      }
#pragma unroll
    for (int ct = 0; ct < 4; ++ct)
#pragma unroll
      for (int ks = 0; ks < 2; ++ks) {
        int col = wc * 64 + ct * 16 + lo;
        bfr[ct][ks] = *(const bf16x8*)&b_lds[col * 64 + (((ks * 4 + g) ^ (col & 7)) << 3)];
      }
    __builtin_amdgcn_s_setprio(1);
#pragma unroll
    for (int ks = 0; ks < 2; ++ks)
#pragma unroll
      for (int rt = 0; rt < 4; ++rt)
#pragma unroll
        for (int ct = 0; ct < 4; ++ct)
          acc[rt][ct] = __builtin_amdgcn_mfma_f32_16x16x32_bf16(af[rt][ks], bfr[ct][ks], acc[rt][ct], 0, 0, 0);
    __builtin_amdgcn_s_setprio(0);
    __syncthreads();
  }

  float* wbase = (wv < 2 ? (float*)a_lds : (float*)b_lds) + (wv & 1) * 2048;
  const int grow = bm + wr * 64 + ln;
#pragma unroll
  for (int p = 0; p < 2; ++p) {
#pragma unroll
    for (int rt = 0; rt < 4; ++rt)
#pragma unroll
      for (int cth = 0; cth < 2; ++cth) {
        int ct = 2 * p + cth;
#pragma unroll
        for (int r = 0; r < 4; ++r) {
          int lrow = rt * 16 + 4 * g + r;
          int lcol = cth * 16 + lo;
          float v = acc[rt][ct][r];
          if (MODE == 0) v += bcol[ct];
          wbase[lrow * 32 + (lcol ^ ((lrow & 7) << 2))] = v;
        }
      }
    f32x4 buf[8];
#pragma unroll
    for (int cb = 0; cb < 8; ++cb) {
      int off = (4 * cb) ^ ((ln & 7) << 2);
      buf[cb] = *(const f32x4*)&wbase[ln * 32 + off];
    }
    const size_t obase = (size_t)grow * ldo + bn + wc * 64 + p * 32;
    if (MODE == 2) {
      const float* Rb = R + (size_t)bz * CN + obase;
      float* ob = outF + (size_t)bz * CN + obase;
#pragma unroll
      for (int cb = 0; cb < 8; ++cb) {
        f32x4 t = buf[cb];
        f32x4 rv = *(const f32x4*)&Rb[4 * cb];
#pragma unroll
        for (int j = 0; j < 4; ++j) t[j] += brow + rv[j];
        *(f32x4*)&ob[4 * cb] = t;
      }
    } else {
      float badd = (MODE == 0) ? 0.f : brow;
      ushort_t* ob = outB + (size_t)bz * obStride + obase;
      uint_t wpk[16];
#pragma unroll
      for (int k = 0; k < 16; ++k)
        wpk[k] = pkbf(buf[k >> 1][(k & 1) * 2] + badd, buf[k >> 1][(k & 1) * 2 + 1] + badd);
#pragma unroll
      for (int sidx = 0; sidx < 4; ++sidx) {
        u32x4 t;
        t[0] = wpk[4 * sidx]; t[1] = wpk[4 * sidx + 1];
        t[2] = wpk[4 * sidx + 2]; t[3] = wpk[4 * sidx + 3];
        *(u32x4*)&ob[sidx * 8] = t;
      }
    }
    __syncthreads();
  }
}

// ---------------------------------------------------------------------------
// MFMA flash attention, KT=32, double-buffered LDS, stage-ahead pipeline,
// one barrier per tile. qk: bf16 [B][N][512] (q cols 0-255, k cols 256-511);
// vt: bf16 [B][C][N]. Split-K=4 -> pO bf16 [ks][B][N][C] + pml.
// ---------------------------------------------------------------------------
__device__ __forceinline__ void stage_tile(const ushort_t* __restrict__ ktb,
    const ushort_t* __restrict__ vtb, int k0, ushort_t* kbuf, ushort_t* vbuf,
    int wv, int ln) {
#pragma unroll
  for (int i = 0; i < 4; ++i) {
    int r0 = wv * 8 + i * 2;
    int row = r0 + (ln >> 5);
    GLOAD16(ktb + (size_t)(k0 + row) * 512 + (((ln & 31) ^ (row & 7)) << 3),
            &kbuf[r0 * 256]);
  }
#pragma unroll
  for (int i = 0; i < 4; ++i) {
    int c0 = wv * 64 + i * 16;
    int c = c0 + (ln >> 2);
    GLOAD16(vtb + (size_t)c * N_SP + k0 + (((ln & 3) ^ (c & 3)) << 3),
            &vbuf[c0 * 32]);
  }
}

__global__ __launch_bounds__(256) void attn_mfma(
    const ushort_t* __restrict__ qk, const ushort_t* __restrict__ vt,
    ushort_t* __restrict__ pO, float* __restrict__ pml) {
  __shared__ __align__(16) ushort_t k_lds[2][32 * 256];   // 2 x 16 KB
  __shared__ __align__(16) ushort_t v_lds[2][256 * 32];   // 2 x 16 KB
  __shared__ __align__(16) ushort_t p_lds[4][16 * 32];    // 4 KB

  const int ksplit = blockIdx.y;
  const int b  = blockIdx.z;
  const int q0 = blockIdx.x * 64;
  const int tid = threadIdx.x;
  const int wv = tid >> 6;
  const int ln = tid & 63;
  const int lo = ln & 15;
  const int g  = ln >> 4;

  const ushort_t* qtb = qk + (size_t)b * N_SP * 512;
  const ushort_t* ktb = qtb + 256;
  const ushort_t* vtb = vt + (size_t)b * C_DIM * N_SP;

  bf16x8 qf[8];
  {
    const ushort_t* qp = qtb + (size_t)(q0 + wv * 16 + lo) * 512 + g * 8;
#pragma unroll
    for (int ks = 0; ks < 8; ++ks) qf[ks] = *(const bf16x8*)(qp + ks * 32);
  }

  f32x4 o_acc[16];
#pragma unroll
  for (int i = 0; i < 16; ++i) o_acc[i] = (f32x4)(0.f);
  float m_run[4] = {-1e30f, -1e30f, -1e30f, -1e30f};
  float l_run[4] = {0.f, 0.f, 0.f, 0.f};

  const int kbase = ksplit * 1024;
  stage_tile(ktb, vtb, kbase, k_lds[0], v_lds[0], wv, ln);
  __syncthreads();   // implicit vmcnt(0): tile 0 resident

  for (int t = 0; t < 32; ++t) {
    const int cur = t & 1;
    if (t + 1 < 32)
      stage_tile(ktb, vtb, kbase + (t + 1) * 32, k_lds[cur ^ 1], v_lds[cur ^ 1], wv, ln);

    const ushort_t* kb = k_lds[cur];
    const ushort_t* vb = v_lds[cur];

    // ---- S = Q K^T (16 MFMA)
    f32x4 sacc[2];
    sacc[0] = (f32x4)(0.f); sacc[1] = (f32x4)(0.f);
    __builtin_amdgcn_s_setprio(1);
#pragma unroll
    for (int ks = 0; ks < 8; ++ks)
#pragma unroll
      for (int ct = 0; ct < 2; ++ct) {
        int m = lo + 16 * ct;
        bf16x8 kf = *(const bf16x8*)&kb[(m * 256 + g * 8 + ks * 32) ^ ((m & 7) << 3)];
        sacc[ct] = __builtin_amdgcn_mfma_f32_16x16x32_bf16(qf[ks], kf, sacc[ct], 0, 0, 0);
      }
    __builtin_amdgcn_s_setprio(0);

    // ---- online softmax
    const float scale = 0.0625f;
    float p[2][4], alpha[4];
#pragma unroll
    for (int r = 0; r < 4; ++r) {
      float a = fmaxf(sacc[0][r], sacc[1][r]);
      a = fmaxf(a, __shfl_xor(a, 1));
      a = fmaxf(a, __shfl_xor(a, 2));
      a = fmaxf(a, __shfl_xor(a, 4));
      a = fmaxf(a, __shfl_xor(a, 8));
      float mn = fmaxf(m_run[r], a * scale);
      alpha[r] = __expf(m_run[r] - mn);
      m_run[r] = mn;
      float e0 = __expf(sacc[0][r] * scale - mn);
      float e1 = __expf(sacc[1][r] * scale - mn);
      p[0][r] = e0; p[1][r] = e1;
      float rs = e0 + e1;
      rs += __shfl_xor(rs, 1);
      rs += __shfl_xor(rs, 2);
      rs += __shfl_xor(rs, 4);
      rs += __shfl_xor(rs, 8);
      l_run[r] = l_run[r] * alpha[r] + rs;
    }

    // ---- P -> per-wave LDS (row = query 0..15, 32 keys, chunk-swizzled)
#pragma unroll
    for (int ct = 0; ct < 2; ++ct)
#pragma unroll
      for (int r = 0; r < 4; ++r) {
        int np = 4 * g + r;
        int mp = lo + 16 * ct;
        p_lds[wv][(np * 32 + mp) ^ ((np & 3) << 3)] = f2bf(p[ct][r]);
      }

    // ---- alpha -> O^T layout (query = lane&15), rescale O
    {
      int srcl = (lo >> 2) * 16;
      float a0 = __shfl(alpha[0], srcl);
      float a1 = __shfl(alpha[1], srcl);
      float a2 = __shfl(alpha[2], srcl);
      float a3 = __shfl(alpha[3], srcl);
      int rr = lo & 3;
      float alphaB = rr == 0 ? a0 : rr == 1 ? a1 : (rr == 2 ? a2 : a3);
      if (!__all(alphaB == 1.f)) {
#pragma unroll
        for (int i = 0; i < 16; ++i) o_acc[i] *= alphaB;
      }
    }

    // ---- PV (16 MFMA)
    bf16x8 pf = *(const bf16x8*)&p_lds[wv][(lo * 32 + g * 8) ^ ((lo & 3) << 3)];
    __builtin_amdgcn_s_setprio(1);
#pragma unroll
    for (int ot = 0; ot < 16; ++ot) {
      int c = ot * 16 + lo;
      bf16x8 vf = *(const bf16x8*)&vb[(c * 32 + g * 8) ^ ((c & 3) << 3)];
      o_acc[ot] = __builtin_amdgcn_mfma_f32_16x16x32_bf16(vf, pf, o_acc[ot], 0, 0, 0);
    }
    __builtin_amdgcn_s_setprio(0);

    __syncthreads();   // drains next-tile loads (issued pre-compute) + aligns
  }

  // ---- epilogue: transpose O^T -> rows n (c contiguous), store bf16 partials
  uint_t* tbase = (uint_t*)&k_lds[0][0] + wv * 2048;   // 8KB per wave
#pragma unroll
  for (int ot = 0; ot < 16; ++ot)
#pragma unroll
    for (int p2 = 0; p2 < 2; ++p2) {
      uint_t w32 = pkbf(o_acc[ot][2 * p2], o_acc[ot][2 * p2 + 1]);
      int word = ot * 8 + 2 * g + p2;
      tbase[lo * 128 + (word ^ ((lo & 7) << 2))] = w32;
    }
  {
    const int q = ln >> 2, quarter = ln & 3;
    const size_t row32 = (((size_t)(ksplit * B_DIM + b) * N_SP) + q0 + wv * 16 + q) * (C_DIM / 2);
    uint_t* pO32 = (uint_t*)pO;
#pragma unroll
    for (int cb = 0; cb < 8; ++cb) {
      int off = (quarter * 32 + 4 * cb) ^ ((q & 7) << 2);
      u32x4 tv = *(const u32x4*)&tbase[q * 128 + off];
      *(u32x4*)&pO32[row32 + quarter * 32 + 4 * cb] = tv;
    }
  }
  if (lo == 0) {
#pragma unroll
    for (int r = 0; r < 4; ++r) {
      int qg = q0 + wv * 16 + 4 * g + r;
      size_t mi = (((size_t)(ksplit * B_DIM + b) * N_SP) + qg) * 2;
      pml[mi] = m_run[r];
      pml[mi + 1] = l_run[r];
    }
  }
}

// ---------------------------------------------------------------------------
// Merge 4 split-K partials -> aoT bf16 [B][N][C].
// ---------------------------------------------------------------------------
__global__ __launch_bounds__(256) void merge_kernel(const ushort_t* __restrict__ pO,
    const float* __restrict__ pml, ushort_t* __restrict__ aoT) {
  const int b = blockIdx.y;
  const int n = blockIdx.x * 16 + (threadIdx.x >> 4);
  const int cg = threadIdx.x & 15;
  float mi[4], li[4];
#pragma unroll
  for (int i = 0; i < 4; ++i) {
    size_t o = (((size_t)(i * B_DIM + b) * N_SP) + n) * 2;
    mi[i] = pml[o]; li[i] = pml[o + 1];
  }
  float ms = fmaxf(fmaxf(mi[0], mi[1]), fmaxf(mi[2], mi[3]));
  float wsum = 0.f, wi[4];
#pragma unroll
  for (int i = 0; i < 4; ++i) { wi[i] = __expf(mi[i] - ms); wsum += wi[i] * li[i]; }
  float inv = 1.f / wsum;
  float acc[16] = {};
#pragma unroll
  for (int i = 0; i < 4; ++i) {
    const ushort_t* p = pO + (((size_t)(i * B_DIM + b) * N_SP) + n) * C_DIM + cg * 16;
    u32x4 a = *(const u32x4*)p;
    u32x4 c2 = *(const u32x4*)(p + 8);
#pragma unroll
    for (int j = 0; j < 4; ++j) {
      acc[2 * j]     += wi[i] * bf2f(a[j] & 0xffffu);
      acc[2 * j + 1] += wi[i] * bf2f(a[j] >> 16);
      acc[8 + 2 * j]     += wi[i] * bf2f(c2[j] & 0xffffu);
      acc[8 + 2 * j + 1] += wi[i] * bf2f(c2[j] >> 16);
    }
  }
  ushort_t* ob = aoT + ((size_t)b * N_SP + n) * C_DIM + cg * 16;
  u32x4 o0, o1;
#pragma unroll
  for (int k = 0; k < 4; ++k) o0[k] = pkbf(acc[2 * k] * inv, acc[2 * k + 1] * inv);
#pragma unroll
  for (int k = 0; k < 4; ++k) o1[k] = pkbf(acc[8 + 2 * k] * inv, acc[8 + 2 * k + 1] * inv);
  *(u32x4*)&ob[0] = o0;
  *(u32x4*)&ob[8] = o1;
}

// ---------------------------------------------------------------------------
extern "C" void kernel_launch(void* const* d_in, const int* in_sizes, int n_in,
                              void* d_out, int out_size, void* d_ws, size_t ws_size,
                              hipStream_t stream) {
  const float* x   = (const float*)d_in[0];
  const float* gnw = (const float*)d_in[1];
  const float* gnb = (const float*)d_in[2];
  const float* wq  = (const float*)d_in[3];
  const float* bq  = (const float*)d_in[4];
  const float* wk  = (const float*)d_in[5];
  const float* bk  = (const float*)d_in[6];
  const float* wv  = (const float*)d_in[7];
  const float* bv  = (const float*)d_in[8];
  const float* wp  = (const float*)d_in[9];
  const float* bp  = (const float*)d_in[10];
  float* out = (float*)d_out;

  // ws (bytes): hT 4M | wb 0.5M | qk 8M | vN 4M | aoT 4M | pml 0.25M | pO 16M | gnp
  char* w8 = (char*)d_ws;
  ushort_t* hT  = (ushort_t*)(w8);
  ushort_t* wb  = (ushort_t*)(w8 + (4u << 20));
  ushort_t* qkw = (ushort_t*)(w8 + (4u << 20) + (1u << 19));
  ushort_t* vN  = (ushort_t*)(w8 + (12u << 20) + (1u << 19));
  ushort_t* aoT = (ushort_t*)(w8 + (16u << 20) + (1u << 19));
  float*    pml = (float*)(w8 + (20u << 20) + (1u << 19));
  ushort_t* pO  = (ushort_t*)(w8 + (20u << 20) + (1u << 19) + (1u << 18));
  float*    gnp = (float*)(w8 + (36u << 20) + (1u << 19) + (1u << 18));

  ushort_t* wvb = wb + 131072;
  ushort_t* wpb = wb + 196608;

  wcvt_kernel<<<dim3(256), dim3(256), 0, stream>>>(wq, wk, wv, wp, wb);
  gn_stats<<<dim3(B_DIM * 32, 4), dim3(256), 0, stream>>>(x, gnp);
  gn_apply<<<dim3(B_DIM * 32, 16), dim3(256), 0, stream>>>(x, gnp, gnw, gnb, hT);

  // fused q|k: qk[b][n][512] = hT[n][c] . [wq;wk][o][c]
  mgemm<0><<<dim3(4, 32, B_DIM), dim3(256), 0, stream>>>(
      hT, wb, bq, bk, qkw, nullptr, nullptr, (int)CN, 0, 512, (size_t)N_SP * 512);
  // v[o][n]
  mgemm<1><<<dim3(32, 2, B_DIM), dim3(256), 0, stream>>>(
      wvb, hT, bv, nullptr, vN, nullptr, nullptr, 0, (int)CN, N_SP, CN);

  attn_mfma<<<dim3(64, 4, B_DIM), dim3(256), 0, stream>>>(qkw, vN, pO, pml);
  merge_kernel<<<dim3(256, B_DIM), dim3(256), 0, stream>>>(pO, pml, aoT);

  // out[o][n] = Wp . aoT + bp + x
  mgemm<2><<<dim3(32, 2, B_DIM), dim3(256), 0, stream>>>(
      wpb, aoT, bp, nullptr, nullptr, out, x, 0, (int)CN, N_SP, CN);
}

// Round 7
// 179.694 us; speedup vs baseline: 8.1239x; 1.1692x over previous
//
#include <hip/hip_runtime.h>

#define C_DIM 256
#define N_SP  4096
#define B_DIM 2
#define CPG   8
#define EPS_GN 1e-5f
#define CN ((size_t)C_DIM * N_SP)

typedef unsigned short ushort_t;
typedef unsigned int uint_t;
typedef __attribute__((ext_vector_type(4))) float f32x4;
typedef __attribute__((ext_vector_type(4))) unsigned int u32x4;
typedef __attribute__((ext_vector_type(8))) short bf16x8;

__device__ inline ushort_t f2bf(float f) {
  union { float f; unsigned u; } v; v.f = f;
  unsigned r = v.u + 0x7FFF + ((v.u >> 16) & 1);   // RNE
  return (ushort_t)(r >> 16);
}
__device__ inline uint_t pkbf(float a, float b) {
  return (uint_t)f2bf(a) | ((uint_t)f2bf(b) << 16);
}
__device__ inline float bf2f(uint_t u) {
  union { uint_t u; float f; } v; v.u = u << 16; return v.f;
}

#define GLOAD16(src, dst) __builtin_amdgcn_global_load_lds( \
    (const __attribute__((address_space(1))) unsigned int*)(src), \
    (__attribute__((address_space(3))) unsigned int*)(dst), 16, 0, 0)

// ---------------------------------------------------------------------------
// Weight conversion: 4 x (256x256) fp32 -> bf16 concatenated [wq;wk;wv;wp].
// ---------------------------------------------------------------------------
__global__ __launch_bounds__(256) void wcvt_kernel(const float* __restrict__ wq,
    const float* __restrict__ wk, const float* __restrict__ wv,
    const float* __restrict__ wp, ushort_t* __restrict__ o) {
  int gid = blockIdx.x * 256 + threadIdx.x;
  int i4 = gid * 4;
  const float* s = (i4 < 65536) ? wq : (i4 < 131072) ? wk : (i4 < 196608) ? wv : wp;
  int off = i4 & 65535;
  float4 v = *(const float4*)(s + off);
  uint2 p; p.x = pkbf(v.x, v.y); p.y = pkbf(v.z, v.w);
  *(uint2*)&o[i4] = p;
}

// ---------------------------------------------------------------------------
// GroupNorm stats: grid (64, 4) -> partial (sum, sumsq) per (bg, quarter).
// ---------------------------------------------------------------------------
__global__ __launch_bounds__(256) void gn_stats(const float* __restrict__ x,
    float* __restrict__ part) {
  const int bg = blockIdx.x, sub = blockIdx.y;
  const float* xp = x + (size_t)bg * CPG * N_SP + (size_t)sub * (CPG * N_SP / 4);
  const int tid = threadIdx.x;
  float s = 0.f, ss = 0.f;
  for (int i = tid; i < CPG * N_SP / 4; i += 256) {
    float v = xp[i];
    s += v; ss += v * v;
  }
#pragma unroll
  for (int off = 32; off > 0; off >>= 1) {
    s  += __shfl_down(s, off);
    ss += __shfl_down(ss, off);
  }
  __shared__ float rs[4], rss[4];
  const int wv = tid >> 6, ln = tid & 63;
  if (ln == 0) { rs[wv] = s; rss[wv] = ss; }
  __syncthreads();
  if (tid == 0) {
    part[(bg * 4 + sub) * 2]     = rs[0] + rs[1] + rs[2] + rs[3];
    part[(bg * 4 + sub) * 2 + 1] = rss[0] + rss[1] + rss[2] + rss[3];
  }
}

// ---------------------------------------------------------------------------
// GroupNorm apply -> hT bf16 [B][N][C]. grid (64, 16): (bg, n-chunk of 256).
// ---------------------------------------------------------------------------
__global__ __launch_bounds__(256) void gn_apply(const float* __restrict__ x,
    const float* __restrict__ part, const float* __restrict__ w,
    const float* __restrict__ bgn, ushort_t* __restrict__ hT) {
  const int bg = blockIdx.x;
  const int b = bg >> 5, g = bg & 31;
  const int n0 = blockIdx.y * 256;
  const int tid = threadIdx.x;
  float S = 0.f, SS = 0.f;
#pragma unroll
  for (int i = 0; i < 4; ++i) {
    S  += part[(bg * 4 + i) * 2];
    SS += part[(bg * 4 + i) * 2 + 1];
  }
  const float mean = S / (float)(CPG * N_SP);
  const float var  = SS / (float)(CPG * N_SP) - mean * mean;
  const float rstd = rsqrtf(var + EPS_GN);
  float sc[8], sh[8];
#pragma unroll
  for (int c = 0; c < 8; ++c) {
    sc[c] = w[g * 8 + c] * rstd;
    sh[c] = bgn[g * 8 + c] - mean * sc[c];
  }
  __shared__ float tile[8][256];
  const float* xp = x + ((size_t)b * C_DIM + (size_t)g * CPG) * N_SP;
  for (int i = tid; i < 8 * 256; i += 256) {
    int cc = i >> 8, n = i & 255;
    tile[cc][n] = xp[(size_t)cc * N_SP + n0 + n];
  }
  __syncthreads();
  u32x4 pk4;
#pragma unroll
  for (int p = 0; p < 4; ++p)
    pk4[p] = pkbf(tile[2 * p][tid] * sc[2 * p] + sh[2 * p],
                  tile[2 * p + 1][tid] * sc[2 * p + 1] + sh[2 * p + 1]);
  *(u32x4*)&hT[((size_t)b * N_SP + n0 + tid) * C_DIM + g * 8] = pk4;
}

// ---------------------------------------------------------------------------
// MFMA GEMM, k-contiguous bf16 operands (verified round 4/5).
// ---------------------------------------------------------------------------
template <int MODE>
__global__ __launch_bounds__(256) void mgemm(
    const ushort_t* __restrict__ A, const ushort_t* __restrict__ Bm,
    const float* __restrict__ biasA, const float* __restrict__ biasB,
    ushort_t* __restrict__ outB, float* __restrict__ outF,
    const float* __restrict__ R, int aStride, int bStride, int ldo,
    size_t obStride) {
  __shared__ __align__(16) ushort_t a_lds[128 * 64];
  __shared__ __align__(16) ushort_t b_lds[128 * 64];
  const int bz = blockIdx.z;
  const ushort_t* Ab = A + (size_t)bz * aStride;
  const ushort_t* Bb = Bm + (size_t)bz * bStride;
  const int bm = blockIdx.y * 128, bn = blockIdx.x * 128;
  const int tid = threadIdx.x, wv = tid >> 6, ln = tid & 63;
  const int lo = ln & 15, g = ln >> 4;
  const int wr = wv >> 1, wc = wv & 1;

  f32x4 acc[4][4];
#pragma unroll
  for (int i = 0; i < 4; ++i)
#pragma unroll
    for (int j = 0; j < 4; ++j) acc[i][j] = (f32x4)(0.f);

  float bcol[4];
  float brow = 0.f;
  if (MODE == 0) {
#pragma unroll
    for (int ct = 0; ct < 4; ++ct) {
      int col = bn + wc * 64 + ct * 16 + lo;
      bcol[ct] = (col < 256) ? biasA[col] : biasB[col - 256];
    }
  } else {
    brow = biasA[bm + wr * 64 + ln];
  }

  for (int k0 = 0; k0 < C_DIM; k0 += 64) {
#pragma unroll
    for (int i = 0; i < 4; ++i) {
      int r0 = wv * 32 + i * 8;
      int row = r0 + (ln >> 3);
      GLOAD16(Ab + (size_t)(bm + row) * C_DIM + k0 + (((ln & 7) ^ (row & 7)) << 3),
              &a_lds[r0 * 64]);
      GLOAD16(Bb + (size_t)(bn + row) * C_DIM + k0 + (((ln & 7) ^ (row & 7)) << 3),
              &b_lds[r0 * 64]);
    }
    __syncthreads();
    bf16x8 af[4][2], bfr[4][2];
#pragma unroll
    for (int rt = 0; rt < 4; ++rt)
#pragma unroll
      for (int ks = 0; ks < 2; ++ks) {
        int row = wr * 64 + rt * 16 + lo;
        af[rt][ks] = *(const bf16x8*)&a_lds[row * 64 + (((ks * 4 + g) ^ (row & 7)) << 3)];
      }
#pragma unroll
    for (int ct = 0; ct < 4; ++ct)
#pragma unroll
      for (int ks = 0; ks < 2; ++ks) {
        int col = wc * 64 + ct * 16 + lo;
        bfr[ct][ks] = *(const bf16x8*)&b_lds[col * 64 + (((ks * 4 + g) ^ (col & 7)) << 3)];
      }
    __builtin_amdgcn_s_setprio(1);
#pragma unroll
    for (int ks = 0; ks < 2; ++ks)
#pragma unroll
      for (int rt = 0; rt < 4; ++rt)
#pragma unroll
        for (int ct = 0; ct < 4; ++ct)
          acc[rt][ct] = __builtin_amdgcn_mfma_f32_16x16x32_bf16(af[rt][ks], bfr[ct][ks], acc[rt][ct], 0, 0, 0);
    __builtin_amdgcn_s_setprio(0);
    __syncthreads();
  }

  float* wbase = (wv < 2 ? (float*)a_lds : (float*)b_lds) + (wv & 1) * 2048;
  const int grow = bm + wr * 64 + ln;
#pragma unroll
  for (int p = 0; p < 2; ++p) {
#pragma unroll
    for (int rt = 0; rt < 4; ++rt)
#pragma unroll
      for (int cth = 0; cth < 2; ++cth) {
        int ct = 2 * p + cth;
#pragma unroll
        for (int r = 0; r < 4; ++r) {
          int lrow = rt * 16 + 4 * g + r;
          int lcol = cth * 16 + lo;
          float v = acc[rt][ct][r];
          if (MODE == 0) v += bcol[ct];
          wbase[lrow * 32 + (lcol ^ ((lrow & 7) << 2))] = v;
        }
      }
    f32x4 buf[8];
#pragma unroll
    for (int cb = 0; cb < 8; ++cb) {
      int off = (4 * cb) ^ ((ln & 7) << 2);
      buf[cb] = *(const f32x4*)&wbase[ln * 32 + off];
    }
    const size_t obase = (size_t)grow * ldo + bn + wc * 64 + p * 32;
    if (MODE == 2) {
      const float* Rb = R + (size_t)bz * CN + obase;
      float* ob = outF + (size_t)bz * CN + obase;
#pragma unroll
      for (int cb = 0; cb < 8; ++cb) {
        f32x4 t = buf[cb];
        f32x4 rv = *(const f32x4*)&Rb[4 * cb];
#pragma unroll
        for (int j = 0; j < 4; ++j) t[j] += brow + rv[j];
        *(f32x4*)&ob[4 * cb] = t;
      }
    } else {
      float badd = (MODE == 0) ? 0.f : brow;
      ushort_t* ob = outB + (size_t)bz * obStride + obase;
      uint_t wpk[16];
#pragma unroll
      for (int k = 0; k < 16; ++k)
        wpk[k] = pkbf(buf[k >> 1][(k & 1) * 2] + badd, buf[k >> 1][(k & 1) * 2 + 1] + badd);
#pragma unroll
      for (int sidx = 0; sidx < 4; ++sidx) {
        u32x4 t;
        t[0] = wpk[4 * sidx]; t[1] = wpk[4 * sidx + 1];
        t[2] = wpk[4 * sidx + 2]; t[3] = wpk[4 * sidx + 3];
        *(u32x4*)&ob[sidx * 8] = t;
      }
    }
    __syncthreads();
  }
}

// ---------------------------------------------------------------------------
// MFMA flash attention — round-4-verified body (16 q/wave, KT=64, split-K=4)
// with R5-verified 512-stride fused-qk inputs and a 2-barrier overlap
// pipeline: {stageK; B1; stageV; QK^T; softmax; B2; PV}.
//  - QK^T(t) reads k_lds pre-B2(t); stageK(t+1) writes post-B2(t).
//  - PV(t) reads v_lds before any wave passes B1(t+1); stageV(t+1) after.
//  - p_lds is wave-private. Epilogue reuses k_lds (only QK^T reads it).
// qk: bf16 [B][N][512] (q 0-255 | k 256-511); vt: bf16 [B][C][N].
// ---------------------------------------------------------------------------
__global__ __launch_bounds__(256) void attn_mfma(
    const ushort_t* __restrict__ qk, const ushort_t* __restrict__ vt,
    ushort_t* __restrict__ pO, float* __restrict__ pml) {
  __shared__ __align__(16) ushort_t k_lds[64 * 256];   // 32 KB [m][c]
  __shared__ __align__(16) ushort_t v_lds[256 * 64];   // 32 KB [c][m]
  __shared__ __align__(16) ushort_t p_lds[4][16 * 64]; // 8 KB per-wave

  const int ksplit = blockIdx.y;
  const int b  = blockIdx.z;
  const int q0 = blockIdx.x * 64;
  const int tid = threadIdx.x;
  const int wv = tid >> 6;
  const int ln = tid & 63;
  const int lo = ln & 15;
  const int g  = ln >> 4;

  const ushort_t* qtb = qk + (size_t)b * N_SP * 512;
  const ushort_t* ktb = qtb + 256;
  const ushort_t* vtb = vt + (size_t)b * CN;

  bf16x8 qf[8];
  {
    const ushort_t* qp = qtb + (size_t)(q0 + wv * 16 + lo) * 512 + g * 8;
#pragma unroll
    for (int ks = 0; ks < 8; ++ks) qf[ks] = *(const bf16x8*)(qp + ks * 32);
  }

  f32x4 o_acc[16];
#pragma unroll
  for (int i = 0; i < 16; ++i) o_acc[i] = (f32x4)(0.f);
  float m_run[4] = {-1e30f, -1e30f, -1e30f, -1e30f};
  float l_run[4] = {0.f, 0.f, 0.f, 0.f};

  for (int t = 0; t < 16; ++t) {
    const int k0 = ksplit * 1024 + t * 64;
    // ---- stage K (overlaps previous tile's PV; k_lds safe: QK^T(t-1) pre-B2)
#pragma unroll
    for (int i = 0; i < 8; ++i) {
      int m = wv * 16 + i * 2 + (ln >> 5);
      int sl = ln & 31;
      GLOAD16(ktb + (size_t)(k0 + m) * 512 + ((sl ^ (m & 7)) * 8),
              &k_lds[(wv * 16 + i * 2) * 256]);
    }
    __syncthreads();   // B1: K resident (drains this wave's K loads)

    // ---- stage V (overlaps QK^T + softmax; drained at B2)
#pragma unroll
    for (int i = 0; i < 8; ++i) {
      int c = wv * 64 + i * 8 + (ln >> 3);
      int sl = ln & 7;
      GLOAD16(vtb + (size_t)c * N_SP + k0 + ((sl ^ (c & 7)) * 8),
              &v_lds[(wv * 64 + i * 8) * 64]);
    }

    // ---- S = Q K^T : 4 col-tiles x 8 k-steps
    f32x4 sacc[4];
#pragma unroll
    for (int ct = 0; ct < 4; ++ct) sacc[ct] = (f32x4)(0.f);
    __builtin_amdgcn_s_setprio(1);
#pragma unroll
    for (int ks = 0; ks < 8; ++ks) {
#pragma unroll
      for (int ct = 0; ct < 4; ++ct) {
        int m = lo + 16 * ct;
        bf16x8 kf = *(const bf16x8*)&k_lds[(m * 256 + g * 8 + ks * 32) ^ ((m & 7) << 3)];
        sacc[ct] = __builtin_amdgcn_mfma_f32_16x16x32_bf16(qf[ks], kf, sacc[ct], 0, 0, 0);
      }
    }
    __builtin_amdgcn_s_setprio(0);

    // ---- online softmax (rows 4g+r live across the 16-lane group)
    const float scale = 0.0625f;
    float p[4][4], alpha[4];
#pragma unroll
    for (int r = 0; r < 4; ++r) {
      float a = fmaxf(fmaxf(sacc[0][r], sacc[1][r]), fmaxf(sacc[2][r], sacc[3][r]));
      a = fmaxf(a, __shfl_xor(a, 1));
      a = fmaxf(a, __shfl_xor(a, 2));
      a = fmaxf(a, __shfl_xor(a, 4));
      a = fmaxf(a, __shfl_xor(a, 8));
      float mn = fmaxf(m_run[r], a * scale);
      alpha[r] = __expf(m_run[r] - mn);
      m_run[r] = mn;
      float rsum = 0.f;
#pragma unroll
      for (int ct = 0; ct < 4; ++ct) {
        float e = __expf(sacc[ct][r] * scale - mn);
        p[ct][r] = e; rsum += e;
      }
      rsum += __shfl_xor(rsum, 1);
      rsum += __shfl_xor(rsum, 2);
      rsum += __shfl_xor(rsum, 4);
      rsum += __shfl_xor(rsum, 8);
      l_run[r] = l_run[r] * alpha[r] + rsum;
    }

    // ---- P -> per-wave LDS (bf16), swizzled [n'][m]
#pragma unroll
    for (int ct = 0; ct < 4; ++ct)
#pragma unroll
      for (int r = 0; r < 4; ++r) {
        int np = 4 * g + r;
        int mp = lo + 16 * ct;
        p_lds[wv][(np * 64 + mp) ^ ((np & 7) << 3)] = f2bf(p[ct][r]);
      }

    // ---- alpha -> O^T layout (query = lane&15), rescale O
    {
      int srcl = (lo >> 2) * 16;
      float a0 = __shfl(alpha[0], srcl);
      float a1 = __shfl(alpha[1], srcl);
      float a2 = __shfl(alpha[2], srcl);
      float a3 = __shfl(alpha[3], srcl);
      int rr = lo & 3;
      float alphaB = rr == 0 ? a0 : rr == 1 ? a1 : (rr == 2 ? a2 : a3);
      if (!__all(alphaB == 1.f)) {
#pragma unroll
        for (int i = 0; i < 16; ++i) o_acc[i] *= alphaB;
      }
    }

    __syncthreads();   // B2: drains V loads; separates QK^T reads from next stageK

    // ---- PV: O^T = V^T P^T
    __builtin_amdgcn_s_setprio(1);
#pragma unroll
    for (int ks2 = 0; ks2 < 2; ++ks2) {
      bf16x8 pf = *(const bf16x8*)&p_lds[wv][(lo * 64 + g * 8 + ks2 * 32) ^ ((lo & 7) << 3)];
#pragma unroll
      for (int ot = 0; ot < 16; ++ot) {
        int c = ot * 16 + lo;
        bf16x8 vf = *(const bf16x8*)&v_lds[(c * 64 + g * 8 + ks2 * 32) ^ ((c & 7) << 3)];
        o_acc[ot] = __builtin_amdgcn_mfma_f32_16x16x32_bf16(vf, pf, o_acc[ot], 0, 0, 0);
      }
    }
    __builtin_amdgcn_s_setprio(0);
    // no end barrier: next stageK only conflicts with QK^T reads (pre-B2)
  }

  // ---- epilogue: transpose O^T (c,q) -> rows n with c contiguous, bf16 partials
  uint_t* tbase = (uint_t*)&k_lds[0] + wv * 2048;   // 8KB per wave
#pragma unroll
  for (int ot = 0; ot < 16; ++ot)
#pragma unroll
    for (int p2 = 0; p2 < 2; ++p2) {
      uint_t w32 = pkbf(o_acc[ot][2 * p2], o_acc[ot][2 * p2 + 1]);
      int word = ot * 8 + 2 * g + p2;
      tbase[lo * 128 + (word ^ ((lo & 7) << 2))] = w32;
    }
  {
    const int q = ln >> 2, quarter = ln & 3;
    const size_t row32 = (((size_t)(ksplit * B_DIM + b) * N_SP) + q0 + wv * 16 + q) * (C_DIM / 2);
    uint_t* pO32 = (uint_t*)pO;
#pragma unroll
    for (int cb = 0; cb < 8; ++cb) {
      int off = (quarter * 32 + 4 * cb) ^ ((q & 7) << 2);
      u32x4 tv = *(const u32x4*)&tbase[q * 128 + off];
      *(u32x4*)&pO32[row32 + quarter * 32 + 4 * cb] = tv;
    }
  }
  if (lo == 0) {
#pragma unroll
    for (int r = 0; r < 4; ++r) {
      int qg = q0 + wv * 16 + 4 * g + r;
      size_t mi = (((size_t)(ksplit * B_DIM + b) * N_SP) + qg) * 2;
      pml[mi] = m_run[r];
      pml[mi + 1] = l_run[r];
    }
  }
}

// ---------------------------------------------------------------------------
// Merge 4 split-K partials -> aoT bf16 [B][N][C].
// ---------------------------------------------------------------------------
__global__ __launch_bounds__(256) void merge_kernel(const ushort_t* __restrict__ pO,
    const float* __restrict__ pml, ushort_t* __restrict__ aoT) {
  const int b = blockIdx.y;
  const int n = blockIdx.x * 16 + (threadIdx.x >> 4);
  const int cg = threadIdx.x & 15;
  float mi[4], li[4];
#pragma unroll
  for (int i = 0; i < 4; ++i) {
    size_t o = (((size_t)(i * B_DIM + b) * N_SP) + n) * 2;
    mi[i] = pml[o]; li[i] = pml[o + 1];
  }
  float ms = fmaxf(fmaxf(mi[0], mi[1]), fmaxf(mi[2], mi[3]));
  float wsum = 0.f, wi[4];
#pragma unroll
  for (int i = 0; i < 4; ++i) { wi[i] = __expf(mi[i] - ms); wsum += wi[i] * li[i]; }
  float inv = 1.f / wsum;
  float acc[16] = {};
#pragma unroll
  for (int i = 0; i < 4; ++i) {
    const ushort_t* p = pO + (((size_t)(i * B_DIM + b) * N_SP) + n) * C_DIM + cg * 16;
    u32x4 a = *(const u32x4*)p;
    u32x4 c2 = *(const u32x4*)(p + 8);
#pragma unroll
    for (int j = 0; j < 4; ++j) {
      acc[2 * j]     += wi[i] * bf2f(a[j] & 0xffffu);
      acc[2 * j + 1] += wi[i] * bf2f(a[j] >> 16);
      acc[8 + 2 * j]     += wi[i] * bf2f(c2[j] & 0xffffu);
      acc[8 + 2 * j + 1] += wi[i] * bf2f(c2[j] >> 16);
    }
  }
  ushort_t* ob = aoT + ((size_t)b * N_SP + n) * C_DIM + cg * 16;
  u32x4 o0, o1;
#pragma unroll
  for (int k = 0; k < 4; ++k) o0[k] = pkbf(acc[2 * k] * inv, acc[2 * k + 1] * inv);
#pragma unroll
  for (int k = 0; k < 4; ++k) o1[k] = pkbf(acc[8 + 2 * k] * inv, acc[8 + 2 * k + 1] * inv);
  *(u32x4*)&ob[0] = o0;
  *(u32x4*)&ob[8] = o1;
}

// ---------------------------------------------------------------------------
extern "C" void kernel_launch(void* const* d_in, const int* in_sizes, int n_in,
                              void* d_out, int out_size, void* d_ws, size_t ws_size,
                              hipStream_t stream) {
  const float* x   = (const float*)d_in[0];
  const float* gnw = (const float*)d_in[1];
  const float* gnb = (const float*)d_in[2];
  const float* wq  = (const float*)d_in[3];
  const float* bq  = (const float*)d_in[4];
  const float* wk  = (const float*)d_in[5];
  const float* bk  = (const float*)d_in[6];
  const float* wv  = (const float*)d_in[7];
  const float* bv  = (const float*)d_in[8];
  const float* wp  = (const float*)d_in[9];
  const float* bp  = (const float*)d_in[10];
  float* out = (float*)d_out;

  // ws (bytes): hT 4M | wb 0.5M | qk 8M | vN 4M | aoT 4M | pml 0.25M | pO 16M | gnp
  char* w8 = (char*)d_ws;
  ushort_t* hT  = (ushort_t*)(w8);
  ushort_t* wb  = (ushort_t*)(w8 + (4u << 20));
  ushort_t* qkw = (ushort_t*)(w8 + (4u << 20) + (1u << 19));
  ushort_t* vN  = (ushort_t*)(w8 + (12u << 20) + (1u << 19));
  ushort_t* aoT = (ushort_t*)(w8 + (16u << 20) + (1u << 19));
  float*    pml = (float*)(w8 + (20u << 20) + (1u << 19));
  ushort_t* pO  = (ushort_t*)(w8 + (20u << 20) + (1u << 19) + (1u << 18));
  float*    gnp = (float*)(w8 + (36u << 20) + (1u << 19) + (1u << 18));

  ushort_t* wvb = wb + 131072;
  ushort_t* wpb = wb + 196608;

  wcvt_kernel<<<dim3(256), dim3(256), 0, stream>>>(wq, wk, wv, wp, wb);
  gn_stats<<<dim3(B_DIM * 32, 4), dim3(256), 0, stream>>>(x, gnp);
  gn_apply<<<dim3(B_DIM * 32, 16), dim3(256), 0, stream>>>(x, gnp, gnw, gnb, hT);

  mgemm<0><<<dim3(4, 32, B_DIM), dim3(256), 0, stream>>>(
      hT, wb, bq, bk, qkw, nullptr, nullptr, (int)CN, 0, 512, (size_t)N_SP * 512);
  mgemm<1><<<dim3(32, 2, B_DIM), dim3(256), 0, stream>>>(
      wvb, hT, bv, nullptr, vN, nullptr, nullptr, 0, (int)CN, N_SP, CN);

  attn_mfma<<<dim3(64, 4, B_DIM), dim3(256), 0, stream>>>(qkw, vN, pO, pml);
  merge_kernel<<<dim3(256, B_DIM), dim3(256), 0, stream>>>(pO, pml, aoT);

  mgemm<2><<<dim3(32, 2, B_DIM), dim3(256), 0, stream>>>(
      wpb, aoT, bp, nullptr, nullptr, out, x, 0, (int)CN, N_SP, CN);
}

// Round 8
// 145.930 us; speedup vs baseline: 10.0036x; 1.2314x over previous
//
#include <hip/hip_runtime.h>

#define C_DIM 256
#define N_SP  4096
#define B_DIM 2
#define CPG   8
#define EPS_GN 1e-5f
#define CN ((size_t)C_DIM * N_SP)

typedef unsigned short ushort_t;
typedef unsigned int uint_t;
typedef __attribute__((ext_vector_type(4))) float f32x4;
typedef __attribute__((ext_vector_type(4))) unsigned int u32x4;
typedef __attribute__((ext_vector_type(8))) short bf16x8;

__device__ inline ushort_t f2bf(float f) {
  union { float f; unsigned u; } v; v.f = f;
  unsigned r = v.u + 0x7FFF + ((v.u >> 16) & 1);   // RNE
  return (ushort_t)(r >> 16);
}
__device__ inline uint_t pkbf(float a, float b) {
  return (uint_t)f2bf(a) | ((uint_t)f2bf(b) << 16);
}
__device__ inline float bf2f(uint_t u) {
  union { uint_t u; float f; } v; v.u = u << 16; return v.f;
}

#define GLOAD16(src, dst) __builtin_amdgcn_global_load_lds( \
    (const __attribute__((address_space(1))) unsigned int*)(src), \
    (__attribute__((address_space(3))) unsigned int*)(dst), 16, 0, 0)

// ---------------------------------------------------------------------------
// Weight conversion: 4 x (256x256) fp32 -> bf16 concatenated [wq;wk;wv;wp].
// ---------------------------------------------------------------------------
__global__ __launch_bounds__(256) void wcvt_kernel(const float* __restrict__ wq,
    const float* __restrict__ wk, const float* __restrict__ wv,
    const float* __restrict__ wp, ushort_t* __restrict__ o) {
  int gid = blockIdx.x * 256 + threadIdx.x;
  int i4 = gid * 4;
  const float* s = (i4 < 65536) ? wq : (i4 < 131072) ? wk : (i4 < 196608) ? wv : wp;
  int off = i4 & 65535;
  float4 v = *(const float4*)(s + off);
  uint2 p; p.x = pkbf(v.x, v.y); p.y = pkbf(v.z, v.w);
  *(uint2*)&o[i4] = p;
}

// ---------------------------------------------------------------------------
// GroupNorm stats: grid (64, 4) -> partial (sum, sumsq) per (bg, quarter).
// ---------------------------------------------------------------------------
__global__ __launch_bounds__(256) void gn_stats(const float* __restrict__ x,
    float* __restrict__ part) {
  const int bg = blockIdx.x, sub = blockIdx.y;
  const float* xp = x + (size_t)bg * CPG * N_SP + (size_t)sub * (CPG * N_SP / 4);
  const int tid = threadIdx.x;
  float s = 0.f, ss = 0.f;
  for (int i = tid; i < CPG * N_SP / 4; i += 256) {
    float v = xp[i];
    s += v; ss += v * v;
  }
#pragma unroll
  for (int off = 32; off > 0; off >>= 1) {
    s  += __shfl_down(s, off);
    ss += __shfl_down(ss, off);
  }
  __shared__ float rs[4], rss[4];
  const int wv = tid >> 6, ln = tid & 63;
  if (ln == 0) { rs[wv] = s; rss[wv] = ss; }
  __syncthreads();
  if (tid == 0) {
    part[(bg * 4 + sub) * 2]     = rs[0] + rs[1] + rs[2] + rs[3];
    part[(bg * 4 + sub) * 2 + 1] = rss[0] + rss[1] + rss[2] + rss[3];
  }
}

// ---------------------------------------------------------------------------
// GroupNorm apply -> hT bf16 [B][N][C]. grid (64, 16): (bg, n-chunk of 256).
// ---------------------------------------------------------------------------
__global__ __launch_bounds__(256) void gn_apply(const float* __restrict__ x,
    const float* __restrict__ part, const float* __restrict__ w,
    const float* __restrict__ bgn, ushort_t* __restrict__ hT) {
  const int bg = blockIdx.x;
  const int b = bg >> 5, g = bg & 31;
  const int n0 = blockIdx.y * 256;
  const int tid = threadIdx.x;
  float S = 0.f, SS = 0.f;
#pragma unroll
  for (int i = 0; i < 4; ++i) {
    S  += part[(bg * 4 + i) * 2];
    SS += part[(bg * 4 + i) * 2 + 1];
  }
  const float mean = S / (float)(CPG * N_SP);
  const float var  = SS / (float)(CPG * N_SP) - mean * mean;
  const float rstd = rsqrtf(var + EPS_GN);
  float sc[8], sh[8];
#pragma unroll
  for (int c = 0; c < 8; ++c) {
    sc[c] = w[g * 8 + c] * rstd;
    sh[c] = bgn[g * 8 + c] - mean * sc[c];
  }
  __shared__ float tile[8][256];
  const float* xp = x + ((size_t)b * C_DIM + (size_t)g * CPG) * N_SP;
  for (int i = tid; i < 8 * 256; i += 256) {
    int cc = i >> 8, n = i & 255;
    tile[cc][n] = xp[(size_t)cc * N_SP + n0 + n];
  }
  __syncthreads();
  u32x4 pk4;
#pragma unroll
  for (int p = 0; p < 4; ++p)
    pk4[p] = pkbf(tile[2 * p][tid] * sc[2 * p] + sh[2 * p],
                  tile[2 * p + 1][tid] * sc[2 * p + 1] + sh[2 * p + 1]);
  *(u32x4*)&hT[((size_t)b * N_SP + n0 + tid) * C_DIM + g * 8] = pk4;
}

// ---------------------------------------------------------------------------
// MFMA GEMM, k-contiguous bf16 operands (verified round 4/5).
// ---------------------------------------------------------------------------
template <int MODE>
__global__ __launch_bounds__(256) void mgemm(
    const ushort_t* __restrict__ A, const ushort_t* __restrict__ Bm,
    const float* __restrict__ biasA, const float* __restrict__ biasB,
    ushort_t* __restrict__ outB, float* __restrict__ outF,
    const float* __restrict__ R, int aStride, int bStride, int ldo,
    size_t obStride) {
  __shared__ __align__(16) ushort_t a_lds[128 * 64];
  __shared__ __align__(16) ushort_t b_lds[128 * 64];
  const int bz = blockIdx.z;
  const ushort_t* Ab = A + (size_t)bz * aStride;
  const ushort_t* Bb = Bm + (size_t)bz * bStride;
  const int bm = blockIdx.y * 128, bn = blockIdx.x * 128;
  const int tid = threadIdx.x, wv = tid >> 6, ln = tid & 63;
  const int lo = ln & 15, g = ln >> 4;
  const int wr = wv >> 1, wc = wv & 1;

  f32x4 acc[4][4];
#pragma unroll
  for (int i = 0; i < 4; ++i)
#pragma unroll
    for (int j = 0; j < 4; ++j) acc[i][j] = (f32x4)(0.f);

  float bcol[4];
  float brow = 0.f;
  if (MODE == 0) {
#pragma unroll
    for (int ct = 0; ct < 4; ++ct) {
      int col = bn + wc * 64 + ct * 16 + lo;
      bcol[ct] = (col < 256) ? biasA[col] : biasB[col - 256];
    }
  } else {
    brow = biasA[bm + wr * 64 + ln];
  }

  for (int k0 = 0; k0 < C_DIM; k0 += 64) {
#pragma unroll
    for (int i = 0; i < 4; ++i) {
      int r0 = wv * 32 + i * 8;
      int row = r0 + (ln >> 3);
      GLOAD16(Ab + (size_t)(bm + row) * C_DIM + k0 + (((ln & 7) ^ (row & 7)) << 3),
              &a_lds[r0 * 64]);
      GLOAD16(Bb + (size_t)(bn + row) * C_DIM + k0 + (((ln & 7) ^ (row & 7)) << 3),
              &b_lds[r0 * 64]);
    }
    __syncthreads();
    bf16x8 af[4][2], bfr[4][2];
#pragma unroll
    for (int rt = 0; rt < 4; ++rt)
#pragma unroll
      for (int ks = 0; ks < 2; ++ks) {
        int row = wr * 64 + rt * 16 + lo;
        af[rt][ks] = *(const bf16x8*)&a_lds[row * 64 + (((ks * 4 + g) ^ (row & 7)) << 3)];
      }
#pragma unroll
    for (int ct = 0; ct < 4; ++ct)
#pragma unroll
      for (int ks = 0; ks < 2; ++ks) {
        int col = wc * 64 + ct * 16 + lo;
        bfr[ct][ks] = *(const bf16x8*)&b_lds[col * 64 + (((ks * 4 + g) ^ (col & 7)) << 3)];
      }
    __builtin_amdgcn_s_setprio(1);
#pragma unroll
    for (int ks = 0; ks < 2; ++ks)
#pragma unroll
      for (int rt = 0; rt < 4; ++rt)
#pragma unroll
        for (int ct = 0; ct < 4; ++ct)
          acc[rt][ct] = __builtin_amdgcn_mfma_f32_16x16x32_bf16(af[rt][ks], bfr[ct][ks], acc[rt][ct], 0, 0, 0);
    __builtin_amdgcn_s_setprio(0);
    __syncthreads();
  }

  float* wbase = (wv < 2 ? (float*)a_lds : (float*)b_lds) + (wv & 1) * 2048;
  const int grow = bm + wr * 64 + ln;
#pragma unroll
  for (int p = 0; p < 2; ++p) {
#pragma unroll
    for (int rt = 0; rt < 4; ++rt)
#pragma unroll
      for (int cth = 0; cth < 2; ++cth) {
        int ct = 2 * p + cth;
#pragma unroll
        for (int r = 0; r < 4; ++r) {
          int lrow = rt * 16 + 4 * g + r;
          int lcol = cth * 16 + lo;
          float v = acc[rt][ct][r];
          if (MODE == 0) v += bcol[ct];
          wbase[lrow * 32 + (lcol ^ ((lrow & 7) << 2))] = v;
        }
      }
    f32x4 buf[8];
#pragma unroll
    for (int cb = 0; cb < 8; ++cb) {
      int off = (4 * cb) ^ ((ln & 7) << 2);
      buf[cb] = *(const f32x4*)&wbase[ln * 32 + off];
    }
    const size_t obase = (size_t)grow * ldo + bn + wc * 64 + p * 32;
    if (MODE == 2) {
      const float* Rb = R + (size_t)bz * CN + obase;
      float* ob = outF + (size_t)bz * CN + obase;
#pragma unroll
      for (int cb = 0; cb < 8; ++cb) {
        f32x4 t = buf[cb];
        f32x4 rv = *(const f32x4*)&Rb[4 * cb];
#pragma unroll
        for (int j = 0; j < 4; ++j) t[j] += brow + rv[j];
        *(f32x4*)&ob[4 * cb] = t;
      }
    } else {
      float badd = (MODE == 0) ? 0.f : brow;
      ushort_t* ob = outB + (size_t)bz * obStride + obase;
      uint_t wpk[16];
#pragma unroll
      for (int k = 0; k < 16; ++k)
        wpk[k] = pkbf(buf[k >> 1][(k & 1) * 2] + badd, buf[k >> 1][(k & 1) * 2 + 1] + badd);
#pragma unroll
      for (int sidx = 0; sidx < 4; ++sidx) {
        u32x4 t;
        t[0] = wpk[4 * sidx]; t[1] = wpk[4 * sidx + 1];
        t[2] = wpk[4 * sidx + 2]; t[3] = wpk[4 * sidx + 3];
        *(u32x4*)&ob[sidx * 8] = t;
      }
    }
    __syncthreads();
  }
}

// ---------------------------------------------------------------------------
// MFMA flash attention — R4 barrier schedule, SWAPPED QK^T:
//   sacc[kt] = mfma(kf, qf)  ->  S^T[key=kt*16+4g+r][query=lane&15].
// Softmax is lane-local (15 fmax + 2 shfl); no alpha broadcast (o_acc cols
// are already query=lane&15). Defer-max (THR=8) skips most rescales.
// qk: bf16 [B][N][512] (q 0-255 | k 256-511); vt: bf16 [B][C][N].
// Split-K=4 -> pO bf16 [ks][B][N][C] (unnormalized) + pml (m,l).
// ---------------------------------------------------------------------------
__global__ __launch_bounds__(256) void attn_mfma(
    const ushort_t* __restrict__ qk, const ushort_t* __restrict__ vt,
    ushort_t* __restrict__ pO, float* __restrict__ pml) {
  __shared__ __align__(16) ushort_t k_lds[64 * 256];   // 32 KB [m][c]
  __shared__ __align__(16) ushort_t v_lds[256 * 64];   // 32 KB [c][m]
  __shared__ __align__(16) ushort_t p_lds[4][16 * 64]; // 8 KB per-wave [q][m]

  const int ksplit = blockIdx.y;
  const int b  = blockIdx.z;
  const int q0 = blockIdx.x * 64;
  const int tid = threadIdx.x;
  const int wv = tid >> 6;
  const int ln = tid & 63;
  const int lo = ln & 15;
  const int g  = ln >> 4;

  const ushort_t* qtb = qk + (size_t)b * N_SP * 512;
  const ushort_t* ktb = qtb + 256;
  const ushort_t* vtb = vt + (size_t)b * CN;

  bf16x8 qf[8];
  {
    const ushort_t* qp = qtb + (size_t)(q0 + wv * 16 + lo) * 512 + g * 8;
#pragma unroll
    for (int ks = 0; ks < 8; ++ks) qf[ks] = *(const bf16x8*)(qp + ks * 32);
  }

  f32x4 o_acc[16];
#pragma unroll
  for (int i = 0; i < 16; ++i) o_acc[i] = (f32x4)(0.f);
  float m_run = -1e30f, l_run = 0.f;   // per-lane: query = lane&15

  for (int t = 0; t < 16; ++t) {
    const int k0 = ksplit * 1024 + t * 64;
    // ---- stage K + V (R4 schedule: both up front, one drain at B1)
#pragma unroll
    for (int i = 0; i < 8; ++i) {
      int m = wv * 16 + i * 2 + (ln >> 5);
      int sl = ln & 31;
      GLOAD16(ktb + (size_t)(k0 + m) * 512 + ((sl ^ (m & 7)) * 8),
              &k_lds[(wv * 16 + i * 2) * 256]);
    }
#pragma unroll
    for (int i = 0; i < 8; ++i) {
      int c = wv * 64 + i * 8 + (ln >> 3);
      int sl = ln & 7;
      GLOAD16(vtb + (size_t)c * N_SP + k0 + ((sl ^ (c & 7)) * 8),
              &v_lds[(wv * 64 + i * 8) * 64]);
    }
    __syncthreads();   // B1: K+V resident

    // ---- S^T = K Q^T : 4 key-tiles x 8 k-steps (swapped operands)
    f32x4 sacc[4];
#pragma unroll
    for (int kt = 0; kt < 4; ++kt) sacc[kt] = (f32x4)(0.f);
    __builtin_amdgcn_s_setprio(1);
#pragma unroll
    for (int ks = 0; ks < 8; ++ks) {
#pragma unroll
      for (int kt = 0; kt < 4; ++kt) {
        int m = lo + 16 * kt;
        bf16x8 kf = *(const bf16x8*)&k_lds[(m * 256 + g * 8 + ks * 32) ^ ((m & 7) << 3)];
        sacc[kt] = __builtin_amdgcn_mfma_f32_16x16x32_bf16(kf, qf[ks], sacc[kt], 0, 0, 0);
      }
    }
    __builtin_amdgcn_s_setprio(0);

    // ---- lane-local online softmax (query = lane&15)
    const float scale = 0.0625f;
    float pm = fmaxf(fmaxf(sacc[0][0], sacc[0][1]), fmaxf(sacc[0][2], sacc[0][3]));
#pragma unroll
    for (int kt = 1; kt < 4; ++kt)
      pm = fmaxf(pm, fmaxf(fmaxf(sacc[kt][0], sacc[kt][1]),
                           fmaxf(sacc[kt][2], sacc[kt][3])));
    pm = fmaxf(pm, __shfl_xor(pm, 16));
    pm = fmaxf(pm, __shfl_xor(pm, 32));
    pm *= scale;
    float alpha = 1.f;
    if (!__all(pm <= m_run + 8.f)) {     // defer-max: tolerate e^8 in P
      float mn = fmaxf(m_run, pm);
      alpha = __expf(m_run - mn);
      m_run = mn;
    }
    float rsum = 0.f;
#pragma unroll
    for (int kt = 0; kt < 4; ++kt)
#pragma unroll
      for (int r = 0; r < 4; ++r) {
        float e = __expf(sacc[kt][r] * scale - m_run);
        rsum += e;
        p_lds[wv][(lo * 64 + kt * 16 + 4 * g + r) ^ ((lo & 7) << 3)] = f2bf(e);
      }
    rsum += __shfl_xor(rsum, 16);
    rsum += __shfl_xor(rsum, 32);
    l_run = l_run * alpha + rsum;
    if (!__all(alpha == 1.f)) {
#pragma unroll
      for (int i = 0; i < 16; ++i) o_acc[i] *= alpha;
    }

    // ---- PV: O^T = V^T P^T  (p_lds wave-private; lgkmcnt ordering suffices)
    __builtin_amdgcn_s_setprio(1);
#pragma unroll
    for (int ks2 = 0; ks2 < 2; ++ks2) {
      bf16x8 pf = *(const bf16x8*)&p_lds[wv][(lo * 64 + g * 8 + ks2 * 32) ^ ((lo & 7) << 3)];
#pragma unroll
      for (int ot = 0; ot < 16; ++ot) {
        int c = ot * 16 + lo;
        bf16x8 vf = *(const bf16x8*)&v_lds[(c * 64 + g * 8 + ks2 * 32) ^ ((c & 7) << 3)];
        o_acc[ot] = __builtin_amdgcn_mfma_f32_16x16x32_bf16(vf, pf, o_acc[ot], 0, 0, 0);
      }
    }
    __builtin_amdgcn_s_setprio(0);
    __syncthreads();   // B2: all LDS reads done before next tile's stage
  }

  // ---- epilogue: transpose O^T (c,q) -> rows n with c contiguous, bf16 partials
  uint_t* tbase = (uint_t*)&k_lds[0] + wv * 2048;   // 8KB per wave
#pragma unroll
  for (int ot = 0; ot < 16; ++ot)
#pragma unroll
    for (int p2 = 0; p2 < 2; ++p2) {
      uint_t w32 = pkbf(o_acc[ot][2 * p2], o_acc[ot][2 * p2 + 1]);
      int word = ot * 8 + 2 * g + p2;
      tbase[lo * 128 + (word ^ ((lo & 7) << 2))] = w32;
    }
  {
    const int q = ln >> 2, quarter = ln & 3;
    const size_t row32 = (((size_t)(ksplit * B_DIM + b) * N_SP) + q0 + wv * 16 + q) * (C_DIM / 2);
    uint_t* pO32 = (uint_t*)pO;
#pragma unroll
    for (int cb = 0; cb < 8; ++cb) {
      int off = (quarter * 32 + 4 * cb) ^ ((q & 7) << 2);
      u32x4 tv = *(const u32x4*)&tbase[q * 128 + off];
      *(u32x4*)&pO32[row32 + quarter * 32 + 4 * cb] = tv;
    }
  }
  if (g == 0) {
    int qn = q0 + wv * 16 + lo;
    size_t mi = (((size_t)(ksplit * B_DIM + b) * N_SP) + qn) * 2;
    pml[mi] = m_run;
    pml[mi + 1] = l_run;
  }
}

// ---------------------------------------------------------------------------
// Merge 4 split-K partials -> aoT bf16 [B][N][C].
// ---------------------------------------------------------------------------
__global__ __launch_bounds__(256) void merge_kernel(const ushort_t* __restrict__ pO,
    const float* __restrict__ pml, ushort_t* __restrict__ aoT) {
  const int b = blockIdx.y;
  const int n = blockIdx.x * 16 + (threadIdx.x >> 4);
  const int cg = threadIdx.x & 15;
  float mi[4], li[4];
#pragma unroll
  for (int i = 0; i < 4; ++i) {
    size_t o = (((size_t)(i * B_DIM + b) * N_SP) + n) * 2;
    mi[i] = pml[o]; li[i] = pml[o + 1];
  }
  float ms = fmaxf(fmaxf(mi[0], mi[1]), fmaxf(mi[2], mi[3]));
  float wsum = 0.f, wi[4];
#pragma unroll
  for (int i = 0; i < 4; ++i) { wi[i] = __expf(mi[i] - ms); wsum += wi[i] * li[i]; }
  float inv = 1.f / wsum;
  float acc[16] = {};
#pragma unroll
  for (int i = 0; i < 4; ++i) {
    const ushort_t* p = pO + (((size_t)(i * B_DIM + b) * N_SP) + n) * C_DIM + cg * 16;
    u32x4 a = *(const u32x4*)p;
    u32x4 c2 = *(const u32x4*)(p + 8);
#pragma unroll
    for (int j = 0; j < 4; ++j) {
      acc[2 * j]     += wi[i] * bf2f(a[j] & 0xffffu);
      acc[2 * j + 1] += wi[i] * bf2f(a[j] >> 16);
      acc[8 + 2 * j]     += wi[i] * bf2f(c2[j] & 0xffffu);
      acc[8 + 2 * j + 1] += wi[i] * bf2f(c2[j] >> 16);
    }
  }
  ushort_t* ob = aoT + ((size_t)b * N_SP + n) * C_DIM + cg * 16;
  u32x4 o0, o1;
#pragma unroll
  for (int k = 0; k < 4; ++k) o0[k] = pkbf(acc[2 * k] * inv, acc[2 * k + 1] * inv);
#pragma unroll
  for (int k = 0; k < 4; ++k) o1[k] = pkbf(acc[8 + 2 * k] * inv, acc[8 + 2 * k + 1] * inv);
  *(u32x4*)&ob[0] = o0;
  *(u32x4*)&ob[8] = o1;
}

// ---------------------------------------------------------------------------
extern "C" void kernel_launch(void* const* d_in, const int* in_sizes, int n_in,
                              void* d_out, int out_size, void* d_ws, size_t ws_size,
                              hipStream_t stream) {
  const float* x   = (const float*)d_in[0];
  const float* gnw = (const float*)d_in[1];
  const float* gnb = (const float*)d_in[2];
  const float* wq  = (const float*)d_in[3];
  const float* bq  = (const float*)d_in[4];
  const float* wk  = (const float*)d_in[5];
  const float* bk  = (const float*)d_in[6];
  const float* wv  = (const float*)d_in[7];
  const float* bv  = (const float*)d_in[8];
  const float* wp  = (const float*)d_in[9];
  const float* bp  = (const float*)d_in[10];
  float* out = (float*)d_out;

  // ws (bytes): hT 4M | wb 0.5M | qk 8M | vN 4M | aoT 4M | pml 0.25M | pO 16M | gnp
  char* w8 = (char*)d_ws;
  ushort_t* hT  = (ushort_t*)(w8);
  ushort_t* wb  = (ushort_t*)(w8 + (4u << 20));
  ushort_t* qkw = (ushort_t*)(w8 + (4u << 20) + (1u << 19));
  ushort_t* vN  = (ushort_t*)(w8 + (12u << 20) + (1u << 19));
  ushort_t* aoT = (ushort_t*)(w8 + (16u << 20) + (1u << 19));
  float*    pml = (float*)(w8 + (20u << 20) + (1u << 19));
  ushort_t* pO  = (ushort_t*)(w8 + (20u << 20) + (1u << 19) + (1u << 18));
  float*    gnp = (float*)(w8 + (36u << 20) + (1u << 19) + (1u << 18));

  ushort_t* wvb = wb + 131072;
  ushort_t* wpb = wb + 196608;

  wcvt_kernel<<<dim3(256), dim3(256), 0, stream>>>(wq, wk, wv, wp, wb);
  gn_stats<<<dim3(B_DIM * 32, 4), dim3(256), 0, stream>>>(x, gnp);
  gn_apply<<<dim3(B_DIM * 32, 16), dim3(256), 0, stream>>>(x, gnp, gnw, gnb, hT);

  mgemm<0><<<dim3(4, 32, B_DIM), dim3(256), 0, stream>>>(
      hT, wb, bq, bk, qkw, nullptr, nullptr, (int)CN, 0, 512, (size_t)N_SP * 512);
  mgemm<1><<<dim3(32, 2, B_DIM), dim3(256), 0, stream>>>(
      wvb, hT, bv, nullptr, vN, nullptr, nullptr, 0, (int)CN, N_SP, CN);

  attn_mfma<<<dim3(64, 4, B_DIM), dim3(256), 0, stream>>>(qkw, vN, pO, pml);
  merge_kernel<<<dim3(256, B_DIM), dim3(256), 0, stream>>>(pO, pml, aoT);

  mgemm<2><<<dim3(32, 2, B_DIM), dim3(256), 0, stream>>>(
      wpb, aoT, bp, nullptr, nullptr, out, x, 0, (int)CN, N_SP, CN);
}

// Round 9
// 125.057 us; speedup vs baseline: 11.6733x; 1.1669x over previous
//
#include <hip/hip_runtime.h>

#define C_DIM 256
#define N_SP  4096
#define B_DIM 2
#define CPG   8
#define EPS_GN 1e-5f
#define CN ((size_t)C_DIM * N_SP)

typedef unsigned short ushort_t;
typedef unsigned int uint_t;
typedef __attribute__((ext_vector_type(4))) float f32x4;
typedef __attribute__((ext_vector_type(16))) float f32x16;
typedef __attribute__((ext_vector_type(4))) unsigned int u32x4;
typedef __attribute__((ext_vector_type(8))) short bf16x8;

__device__ inline ushort_t f2bf(float f) {
  union { float f; unsigned u; } v; v.f = f;
  unsigned r = v.u + 0x7FFF + ((v.u >> 16) & 1);   // RNE
  return (ushort_t)(r >> 16);
}
__device__ inline uint_t pkbf(float a, float b) {
  return (uint_t)f2bf(a) | ((uint_t)f2bf(b) << 16);
}
__device__ inline float bf2f(uint_t u) {
  union { uint_t u; float f; } v; v.u = u << 16; return v.f;
}

#define GLOAD16(src, dst) __builtin_amdgcn_global_load_lds( \
    (const __attribute__((address_space(1))) unsigned int*)(src), \
    (__attribute__((address_space(3))) unsigned int*)(dst), 16, 0, 0)

// ---------------------------------------------------------------------------
// Weight conversion: 4 x (256x256) fp32 -> bf16 concatenated [wq;wk;wv;wp].
// ---------------------------------------------------------------------------
__global__ __launch_bounds__(256) void wcvt_kernel(const float* __restrict__ wq,
    const float* __restrict__ wk, const float* __restrict__ wv,
    const float* __restrict__ wp, ushort_t* __restrict__ o) {
  int gid = blockIdx.x * 256 + threadIdx.x;
  int i4 = gid * 4;
  const float* s = (i4 < 65536) ? wq : (i4 < 131072) ? wk : (i4 < 196608) ? wv : wp;
  int off = i4 & 65535;
  float4 v = *(const float4*)(s + off);
  uint2 p; p.x = pkbf(v.x, v.y); p.y = pkbf(v.z, v.w);
  *(uint2*)&o[i4] = p;
}

// ---------------------------------------------------------------------------
// GroupNorm stats: grid (64, 4) -> partial (sum, sumsq) per (bg, quarter).
// ---------------------------------------------------------------------------
__global__ __launch_bounds__(256) void gn_stats(const float* __restrict__ x,
    float* __restrict__ part) {
  const int bg = blockIdx.x, sub = blockIdx.y;
  const float* xp = x + (size_t)bg * CPG * N_SP + (size_t)sub * (CPG * N_SP / 4);
  const int tid = threadIdx.x;
  float s = 0.f, ss = 0.f;
  for (int i = tid; i < CPG * N_SP / 4; i += 256) {
    float v = xp[i];
    s += v; ss += v * v;
  }
#pragma unroll
  for (int off = 32; off > 0; off >>= 1) {
    s  += __shfl_down(s, off);
    ss += __shfl_down(ss, off);
  }
  __shared__ float rs[4], rss[4];
  const int wv = tid >> 6, ln = tid & 63;
  if (ln == 0) { rs[wv] = s; rss[wv] = ss; }
  __syncthreads();
  if (tid == 0) {
    part[(bg * 4 + sub) * 2]     = rs[0] + rs[1] + rs[2] + rs[3];
    part[(bg * 4 + sub) * 2 + 1] = rss[0] + rss[1] + rss[2] + rss[3];
  }
}

// ---------------------------------------------------------------------------
// GroupNorm apply -> hT bf16 [B][N][C]. grid (64, 16): (bg, n-chunk of 256).
// ---------------------------------------------------------------------------
__global__ __launch_bounds__(256) void gn_apply(const float* __restrict__ x,
    const float* __restrict__ part, const float* __restrict__ w,
    const float* __restrict__ bgn, ushort_t* __restrict__ hT) {
  const int bg = blockIdx.x;
  const int b = bg >> 5, g = bg & 31;
  const int n0 = blockIdx.y * 256;
  const int tid = threadIdx.x;
  float S = 0.f, SS = 0.f;
#pragma unroll
  for (int i = 0; i < 4; ++i) {
    S  += part[(bg * 4 + i) * 2];
    SS += part[(bg * 4 + i) * 2 + 1];
  }
  const float mean = S / (float)(CPG * N_SP);
  const float var  = SS / (float)(CPG * N_SP) - mean * mean;
  const float rstd = rsqrtf(var + EPS_GN);
  float sc[8], sh[8];
#pragma unroll
  for (int c = 0; c < 8; ++c) {
    sc[c] = w[g * 8 + c] * rstd;
    sh[c] = bgn[g * 8 + c] - mean * sc[c];
  }
  __shared__ float tile[8][256];
  const float* xp = x + ((size_t)b * C_DIM + (size_t)g * CPG) * N_SP;
  for (int i = tid; i < 8 * 256; i += 256) {
    int cc = i >> 8, n = i & 255;
    tile[cc][n] = xp[(size_t)cc * N_SP + n0 + n];
  }
  __syncthreads();
  u32x4 pk4;
#pragma unroll
  for (int p = 0; p < 4; ++p)
    pk4[p] = pkbf(tile[2 * p][tid] * sc[2 * p] + sh[2 * p],
                  tile[2 * p + 1][tid] * sc[2 * p + 1] + sh[2 * p + 1]);
  *(u32x4*)&hT[((size_t)b * N_SP + n0 + tid) * C_DIM + g * 8] = pk4;
}

// ---------------------------------------------------------------------------
// MFMA GEMM, k-contiguous bf16 operands (verified round 4/5).
// ---------------------------------------------------------------------------
template <int MODE>
__global__ __launch_bounds__(256) void mgemm(
    const ushort_t* __restrict__ A, const ushort_t* __restrict__ Bm,
    const float* __restrict__ biasA, const float* __restrict__ biasB,
    ushort_t* __restrict__ outB, float* __restrict__ outF,
    const float* __restrict__ R, int aStride, int bStride, int ldo,
    size_t obStride) {
  __shared__ __align__(16) ushort_t a_lds[128 * 64];
  __shared__ __align__(16) ushort_t b_lds[128 * 64];
  const int bz = blockIdx.z;
  const ushort_t* Ab = A + (size_t)bz * aStride;
  const ushort_t* Bb = Bm + (size_t)bz * bStride;
  const int bm = blockIdx.y * 128, bn = blockIdx.x * 128;
  const int tid = threadIdx.x, wv = tid >> 6, ln = tid & 63;
  const int lo = ln & 15, g = ln >> 4;
  const int wr = wv >> 1, wc = wv & 1;

  f32x4 acc[4][4];
#pragma unroll
  for (int i = 0; i < 4; ++i)
#pragma unroll
    for (int j = 0; j < 4; ++j) acc[i][j] = (f32x4)(0.f);

  float bcol[4];
  float brow = 0.f;
  if (MODE == 0) {
#pragma unroll
    for (int ct = 0; ct < 4; ++ct) {
      int col = bn + wc * 64 + ct * 16 + lo;
      bcol[ct] = (col < 256) ? biasA[col] : biasB[col - 256];
    }
  } else {
    brow = biasA[bm + wr * 64 + ln];
  }

  for (int k0 = 0; k0 < C_DIM; k0 += 64) {
#pragma unroll
    for (int i = 0; i < 4; ++i) {
      int r0 = wv * 32 + i * 8;
      int row = r0 + (ln >> 3);
      GLOAD16(Ab + (size_t)(bm + row) * C_DIM + k0 + (((ln & 7) ^ (row & 7)) << 3),
              &a_lds[r0 * 64]);
      GLOAD16(Bb + (size_t)(bn + row) * C_DIM + k0 + (((ln & 7) ^ (row & 7)) << 3),
              &b_lds[r0 * 64]);
    }
    __syncthreads();
    bf16x8 af[4][2], bfr[4][2];
#pragma unroll
    for (int rt = 0; rt < 4; ++rt)
#pragma unroll
      for (int ks = 0; ks < 2; ++ks) {
        int row = wr * 64 + rt * 16 + lo;
        af[rt][ks] = *(const bf16x8*)&a_lds[row * 64 + (((ks * 4 + g) ^ (row & 7)) << 3)];
      }
#pragma unroll
    for (int ct = 0; ct < 4; ++ct)
#pragma unroll
      for (int ks = 0; ks < 2; ++ks) {
        int col = wc * 64 + ct * 16 + lo;
        bfr[ct][ks] = *(const bf16x8*)&b_lds[col * 64 + (((ks * 4 + g) ^ (col & 7)) << 3)];
      }
    __builtin_amdgcn_s_setprio(1);
#pragma unroll
    for (int ks = 0; ks < 2; ++ks)
#pragma unroll
      for (int rt = 0; rt < 4; ++rt)
#pragma unroll
        for (int ct = 0; ct < 4; ++ct)
          acc[rt][ct] = __builtin_amdgcn_mfma_f32_16x16x32_bf16(af[rt][ks], bfr[ct][ks], acc[rt][ct], 0, 0, 0);
    __builtin_amdgcn_s_setprio(0);
    __syncthreads();
  }

  float* wbase = (wv < 2 ? (float*)a_lds : (float*)b_lds) + (wv & 1) * 2048;
  const int grow = bm + wr * 64 + ln;
#pragma unroll
  for (int p = 0; p < 2; ++p) {
#pragma unroll
    for (int rt = 0; rt < 4; ++rt)
#pragma unroll
      for (int cth = 0; cth < 2; ++cth) {
        int ct = 2 * p + cth;
#pragma unroll
        for (int r = 0; r < 4; ++r) {
          int lrow = rt * 16 + 4 * g + r;
          int lcol = cth * 16 + lo;
          float v = acc[rt][ct][r];
          if (MODE == 0) v += bcol[ct];
          wbase[lrow * 32 + (lcol ^ ((lrow & 7) << 2))] = v;
        }
      }
    f32x4 buf[8];
#pragma unroll
    for (int cb = 0; cb < 8; ++cb) {
      int off = (4 * cb) ^ ((ln & 7) << 2);
      buf[cb] = *(const f32x4*)&wbase[ln * 32 + off];
    }
    const size_t obase = (size_t)grow * ldo + bn + wc * 64 + p * 32;
    if (MODE == 2) {
      const float* Rb = R + (size_t)bz * CN + obase;
      float* ob = outF + (size_t)bz * CN + obase;
#pragma unroll
      for (int cb = 0; cb < 8; ++cb) {
        f32x4 t = buf[cb];
        f32x4 rv = *(const f32x4*)&Rb[4 * cb];
#pragma unroll
        for (int j = 0; j < 4; ++j) t[j] += brow + rv[j];
        *(f32x4*)&ob[4 * cb] = t;
      }
    } else {
      float badd = (MODE == 0) ? 0.f : brow;
      ushort_t* ob = outB + (size_t)bz * obStride + obase;
      uint_t wpk[16];
#pragma unroll
      for (int k = 0; k < 16; ++k)
        wpk[k] = pkbf(buf[k >> 1][(k & 1) * 2] + badd, buf[k >> 1][(k & 1) * 2 + 1] + badd);
#pragma unroll
      for (int sidx = 0; sidx < 4; ++sidx) {
        u32x4 t;
        t[0] = wpk[4 * sidx]; t[1] = wpk[4 * sidx + 1];
        t[2] = wpk[4 * sidx + 2]; t[3] = wpk[4 * sidx + 3];
        *(u32x4*)&ob[sidx * 8] = t;
      }
    }
    __syncthreads();
  }
}

// ---------------------------------------------------------------------------
// MFMA flash attention v9 — 32x32x16 MFMA, 32 queries/wave (self-contained),
// KT=64, double-buffered K/V, one barrier per tile.
//  S^T = mfma32(K_frag, Q_frag): col = query = lane&31,
//        row = key = (reg&3)+8*(reg>>2)+4*(lane>>5).  Softmax lane-local.
//  PV:  O^T = mfma32(V_frag, P_frag): row = channel, col = query.
// qk: bf16 [B][N][512] (q 0-255 | k 256-511); vt: bf16 [B][C][N].
// Split-K=4 -> pO bf16 [ks][B][N][C] (unnormalized) + pml (m,l).
// Grid (32, 4, B) = 256 blocks, 1/CU; 146 KB LDS; no VGPR cliff at 4 waves/CU.
// ---------------------------------------------------------------------------
__device__ __forceinline__ void stage_kv(const ushort_t* __restrict__ ktb,
    const ushort_t* __restrict__ vtb, int k0, ushort_t* kbuf, ushort_t* vbuf,
    int wv, int ln) {
#pragma unroll
  for (int i = 0; i < 8; ++i) {
    int m = wv * 16 + i * 2 + (ln >> 5);
    int sl = ln & 31;
    GLOAD16(ktb + (size_t)(k0 + m) * 512 + ((sl ^ (m & 7)) * 8),
            kbuf + (wv * 16 + i * 2) * 256);
  }
#pragma unroll
  for (int i = 0; i < 8; ++i) {
    int c = wv * 64 + i * 8 + (ln >> 3);
    int sl = ln & 7;
    GLOAD16(vtb + (size_t)c * N_SP + k0 + ((sl ^ (c & 7)) * 8),
            vbuf + (wv * 64 + i * 8) * 64);
  }
}

__global__ __launch_bounds__(256, 1) void attn_mfma(
    const ushort_t* __restrict__ qk, const ushort_t* __restrict__ vt,
    ushort_t* __restrict__ pO, float* __restrict__ pml) {
  // layout: k[2][64*256] | v[2][256*64] | p[4][32*72]  = 149504 B
  __shared__ __align__(16) ushort_t lds_all[32768 + 32768 + 9216];

  const int ksplit = blockIdx.y;
  const int b  = blockIdx.z;
  const int q0 = blockIdx.x * 128;
  const int tid = threadIdx.x;
  const int wv = tid >> 6;
  const int ln = tid & 63;
  const int lq = ln & 31;    // query column
  const int lh = ln >> 5;    // k-half selector

  const ushort_t* qtb = qk + (size_t)b * N_SP * 512;
  const ushort_t* ktb = qtb + 256;
  const ushort_t* vtb = vt + (size_t)b * CN;
  ushort_t* p_base = lds_all + 65536 + wv * (32 * 72);

  // Q fragments: B-frag col = lq, k = ks*16 + lh*8 + j  (64 VGPR)
  bf16x8 qf[16];
  {
    const ushort_t* qp = qtb + (size_t)(q0 + wv * 32 + lq) * 512 + lh * 8;
#pragma unroll
    for (int ks = 0; ks < 16; ++ks) qf[ks] = *(const bf16x8*)(qp + ks * 16);
  }

  f32x16 oac[8];
#pragma unroll
  for (int i = 0; i < 8; ++i) oac[i] = (f32x16)(0.f);
  float m_run = -1e30f, l_run = 0.f;   // per-lane: query lq (both halves equal)

  const int kbase = ksplit * 1024;
  stage_kv(ktb, vtb, kbase, lds_all, lds_all + 32768, wv, ln);
  __syncthreads();   // implicit vmcnt(0): tile 0 resident

  for (int t = 0; t < 16; ++t) {
    const int cur = t & 1;
    ushort_t* kb = lds_all + cur * 16384;
    ushort_t* vb = lds_all + 32768 + cur * 16384;
    if (t + 1 < 16)
      stage_kv(ktb, vtb, kbase + (t + 1) * 64,
               lds_all + (cur ^ 1) * 16384,
               lds_all + 32768 + (cur ^ 1) * 16384, wv, ln);

    // ---- S^T = K Q^T : 2 key-subtiles x 16 k-steps (32 MFMA)
    f32x16 s0 = (f32x16)(0.f), s1 = (f32x16)(0.f);
    __builtin_amdgcn_s_setprio(1);
#pragma unroll
    for (int ks = 0; ks < 16; ++ks) {
      bf16x8 kf0 = *(const bf16x8*)&kb[(lq * 256 + ks * 16 + lh * 8) ^ ((lq & 7) << 3)];
      s0 = __builtin_amdgcn_mfma_f32_32x32x16_bf16(kf0, qf[ks], s0, 0, 0, 0);
      int m1 = 32 + lq;
      bf16x8 kf1 = *(const bf16x8*)&kb[(m1 * 256 + ks * 16 + lh * 8) ^ ((m1 & 7) << 3)];
      s1 = __builtin_amdgcn_mfma_f32_32x32x16_bf16(kf1, qf[ks], s1, 0, 0, 0);
    }
    __builtin_amdgcn_s_setprio(0);

    // ---- lane-local online softmax (query = lq; keys = 32 regs across s0,s1)
    const float scale = 0.0625f;
    float mx[16];
#pragma unroll
    for (int r = 0; r < 16; ++r) mx[r] = fmaxf(s0[r], s1[r]);
#pragma unroll
    for (int r = 0; r < 8; ++r) mx[r] = fmaxf(mx[r], mx[r + 8]);
#pragma unroll
    for (int r = 0; r < 4; ++r) mx[r] = fmaxf(mx[r], mx[r + 4]);
    float pm = fmaxf(fmaxf(mx[0], mx[1]), fmaxf(mx[2], mx[3]));
    pm = fmaxf(pm, __shfl_xor(pm, 32));
    pm *= scale;
    float alpha = 1.f;
    if (!__all(pm <= m_run + 8.f)) {     // defer-max (THR=8)
      float mn = fmaxf(m_run, pm);
      alpha = __expf(m_run - mn);
      m_run = mn;
    }
    float es[16];
    float rsum = 0.f;
#pragma unroll
    for (int r = 0; r < 16; ++r) {
      int key = (r & 3) + 8 * (r >> 2) + 4 * lh;
      float e0 = __expf(s0[r] * scale - m_run);
      float e1 = __expf(s1[r] * scale - m_run);
      p_base[lq * 72 + key]      = f2bf(e0);
      p_base[lq * 72 + 32 + key] = f2bf(e1);
      es[r] = e0 + e1;
    }
#pragma unroll
    for (int r = 0; r < 8; ++r) es[r] += es[r + 8];
#pragma unroll
    for (int r = 0; r < 4; ++r) es[r] += es[r + 4];
    rsum = (es[0] + es[1]) + (es[2] + es[3]);
    rsum += __shfl_xor(rsum, 32);
    l_run = l_run * alpha + rsum;
    if (!__all(alpha == 1.f)) {
#pragma unroll
      for (int i = 0; i < 8; ++i) oac[i] *= alpha;
    }

    // ---- PV: O^T = V^T P^T : 8 c-subtiles x 4 k-steps (32 MFMA)
    __builtin_amdgcn_s_setprio(1);
#pragma unroll
    for (int ks2 = 0; ks2 < 4; ++ks2) {
      bf16x8 pf = *(const bf16x8*)&p_base[lq * 72 + ks2 * 16 + lh * 8];
#pragma unroll
      for (int ot = 0; ot < 8; ++ot) {
        int c = ot * 32 + lq;
        bf16x8 vf = *(const bf16x8*)&vb[(c * 64 + ks2 * 16 + lh * 8) ^ ((c & 7) << 3)];
        oac[ot] = __builtin_amdgcn_mfma_f32_32x32x16_bf16(vf, pf, oac[ot], 0, 0, 0);
      }
    }
    __builtin_amdgcn_s_setprio(0);
    __syncthreads();   // drains stage(t+1) loads; fences buffer reuse
  }

  // ---- epilogue: per-wave 32KB fp32 scratch transpose (reuse k/v LDS), then
  // store unnormalized bf16 partials pO[n][c] + (m,l).
  float* sb = (float*)lds_all + wv * 8192;
#pragma unroll
  for (int ot = 0; ot < 8; ++ot)
#pragma unroll
    for (int r = 0; r < 16; ++r) {
      int cl = (r & 3) + 8 * (r >> 2) + 4 * lh;
      int c = ot * 32 + cl;
      sb[lq * 256 + (c ^ ((lq & 7) << 2))] = oac[ot][r];
    }
  {
    const int q = ln >> 1, half = ln & 1;
    const size_t row32 = (((size_t)(ksplit * B_DIM + b) * N_SP) + q0 + wv * 32 + q) * 128;
    uint_t* pO32 = (uint_t*)pO;
#pragma unroll
    for (int j = 0; j < 32; ++j) {
      f32x4 v4 = *(const f32x4*)&sb[q * 256 + ((half * 128 + 4 * j) ^ ((q & 7) << 2))];
      uint2 pk2; pk2.x = pkbf(v4[0], v4[1]); pk2.y = pkbf(v4[2], v4[3]);
      *(uint2*)&pO32[row32 + half * 64 + 2 * j] = pk2;
    }
  }
  if (ln < 32) {
    int qn = q0 + wv * 32 + lq;
    size_t mi = (((size_t)(ksplit * B_DIM + b) * N_SP) + qn) * 2;
    pml[mi] = m_run;
    pml[mi + 1] = l_run;
  }
}

// ---------------------------------------------------------------------------
// Merge 4 split-K partials -> aoT bf16 [B][N][C].
// ---------------------------------------------------------------------------
__global__ __launch_bounds__(256) void merge_kernel(const ushort_t* __restrict__ pO,
    const float* __restrict__ pml, ushort_t* __restrict__ aoT) {
  const int b = blockIdx.y;
  const int n = blockIdx.x * 16 + (threadIdx.x >> 4);
  const int cg = threadIdx.x & 15;
  float mi[4], li[4];
#pragma unroll
  for (int i = 0; i < 4; ++i) {
    size_t o = (((size_t)(i * B_DIM + b) * N_SP) + n) * 2;
    mi[i] = pml[o]; li[i] = pml[o + 1];
  }
  float ms = fmaxf(fmaxf(mi[0], mi[1]), fmaxf(mi[2], mi[3]));
  float wsum = 0.f, wi[4];
#pragma unroll
  for (int i = 0; i < 4; ++i) { wi[i] = __expf(mi[i] - ms); wsum += wi[i] * li[i]; }
  float inv = 1.f / wsum;
  float acc[16] = {};
#pragma unroll
  for (int i = 0; i < 4; ++i) {
    const ushort_t* p = pO + (((size_t)(i * B_DIM + b) * N_SP) + n) * C_DIM + cg * 16;
    u32x4 a = *(const u32x4*)p;
    u32x4 c2 = *(const u32x4*)(p + 8);
#pragma unroll
    for (int j = 0; j < 4; ++j) {
      acc[2 * j]     += wi[i] * bf2f(a[j] & 0xffffu);
      acc[2 * j + 1] += wi[i] * bf2f(a[j] >> 16);
      acc[8 + 2 * j]     += wi[i] * bf2f(c2[j] & 0xffffu);
      acc[8 + 2 * j + 1] += wi[i] * bf2f(c2[j] >> 16);
    }
  }
  ushort_t* ob = aoT + ((size_t)b * N_SP + n) * C_DIM + cg * 16;
  u32x4 o0, o1;
#pragma unroll
  for (int k = 0; k < 4; ++k) o0[k] = pkbf(acc[2 * k] * inv, acc[2 * k + 1] * inv);
#pragma unroll
  for (int k = 0; k < 4; ++k) o1[k] = pkbf(acc[8 + 2 * k] * inv, acc[8 + 2 * k + 1] * inv);
  *(u32x4*)&ob[0] = o0;
  *(u32x4*)&ob[8] = o1;
}

// ---------------------------------------------------------------------------
extern "C" void kernel_launch(void* const* d_in, const int* in_sizes, int n_in,
                              void* d_out, int out_size, void* d_ws, size_t ws_size,
                              hipStream_t stream) {
  const float* x   = (const float*)d_in[0];
  const float* gnw = (const float*)d_in[1];
  const float* gnb = (const float*)d_in[2];
  const float* wq  = (const float*)d_in[3];
  const float* bq  = (const float*)d_in[4];
  const float* wk  = (const float*)d_in[5];
  const float* bk  = (const float*)d_in[6];
  const float* wv  = (const float*)d_in[7];
  const float* bv  = (const float*)d_in[8];
  const float* wp  = (const float*)d_in[9];
  const float* bp  = (const float*)d_in[10];
  float* out = (float*)d_out;

  // ws (bytes): hT 4M | wb 0.5M | qk 8M | vN 4M | aoT 4M | pml 0.25M | pO 16M | gnp
  char* w8 = (char*)d_ws;
  ushort_t* hT  = (ushort_t*)(w8);
  ushort_t* wb  = (ushort_t*)(w8 + (4u << 20));
  ushort_t* qkw = (ushort_t*)(w8 + (4u << 20) + (1u << 19));
  ushort_t* vN  = (ushort_t*)(w8 + (12u << 20) + (1u << 19));
  ushort_t* aoT = (ushort_t*)(w8 + (16u << 20) + (1u << 19));
  float*    pml = (float*)(w8 + (20u << 20) + (1u << 19));
  ushort_t* pO  = (ushort_t*)(w8 + (20u << 20) + (1u << 19) + (1u << 18));
  float*    gnp = (float*)(w8 + (36u << 20) + (1u << 19) + (1u << 18));

  ushort_t* wvb = wb + 131072;
  ushort_t* wpb = wb + 196608;

  wcvt_kernel<<<dim3(256), dim3(256), 0, stream>>>(wq, wk, wv, wp, wb);
  gn_stats<<<dim3(B_DIM * 32, 4), dim3(256), 0, stream>>>(x, gnp);
  gn_apply<<<dim3(B_DIM * 32, 16), dim3(256), 0, stream>>>(x, gnp, gnw, gnb, hT);

  mgemm<0><<<dim3(4, 32, B_DIM), dim3(256), 0, stream>>>(
      hT, wb, bq, bk, qkw, nullptr, nullptr, (int)CN, 0, 512, (size_t)N_SP * 512);
  mgemm<1><<<dim3(32, 2, B_DIM), dim3(256), 0, stream>>>(
      wvb, hT, bv, nullptr, vN, nullptr, nullptr, 0, (int)CN, N_SP, CN);

  attn_mfma<<<dim3(32, 4, B_DIM), dim3(256), 0, stream>>>(qkw, vN, pO, pml);
  merge_kernel<<<dim3(256, B_DIM), dim3(256), 0, stream>>>(pO, pml, aoT);

  mgemm<2><<<dim3(32, 2, B_DIM), dim3(256), 0, stream>>>(
      wpb, aoT, bp, nullptr, nullptr, out, x, 0, (int)CN, N_SP, CN);
}

// Round 10
// 117.983 us; speedup vs baseline: 12.3732x; 1.0600x over previous
//
#include <hip/hip_runtime.h>

#define C_DIM 256
#define N_SP  4096
#define B_DIM 2
#define CPG   8
#define EPS_GN 1e-5f
#define CN ((size_t)C_DIM * N_SP)

typedef unsigned short ushort_t;
typedef unsigned int uint_t;
typedef __attribute__((ext_vector_type(4))) float f32x4;
typedef __attribute__((ext_vector_type(16))) float f32x16;
typedef __attribute__((ext_vector_type(4))) unsigned int u32x4;
typedef __attribute__((ext_vector_type(8))) short bf16x8;

// HW packed f32->bf16 (RNE), lo = a, hi = b  [T12 recipe: no builtin on gfx950]
__device__ inline uint_t pkbf(float a, float b) {
  uint_t r;
  asm("v_cvt_pk_bf16_f32 %0, %1, %2" : "=v"(r) : "v"(a), "v"(b));
  return r;
}
__device__ inline float bf2f(uint_t u) {
  union { uint_t u; float f; } v; v.u = u << 16; return v.f;
}

#define GLOAD16(src, dst) __builtin_amdgcn_global_load_lds( \
    (const __attribute__((address_space(1))) unsigned int*)(src), \
    (__attribute__((address_space(3))) unsigned int*)(dst), 16, 0, 0)

// ---------------------------------------------------------------------------
// Weight conversion: 4 x (256x256) fp32 -> bf16 concatenated [wq;wk;wv;wp].
// ---------------------------------------------------------------------------
__global__ __launch_bounds__(256) void wcvt_kernel(const float* __restrict__ wq,
    const float* __restrict__ wk, const float* __restrict__ wv,
    const float* __restrict__ wp, ushort_t* __restrict__ o) {
  int gid = blockIdx.x * 256 + threadIdx.x;
  int i4 = gid * 4;
  const float* s = (i4 < 65536) ? wq : (i4 < 131072) ? wk : (i4 < 196608) ? wv : wp;
  int off = i4 & 65535;
  float4 v = *(const float4*)(s + off);
  uint2 p; p.x = pkbf(v.x, v.y); p.y = pkbf(v.z, v.w);
  *(uint2*)&o[i4] = p;
}

// ---------------------------------------------------------------------------
// GroupNorm stats: grid (64, 4) -> partial (sum, sumsq) per (bg, quarter).
// ---------------------------------------------------------------------------
__global__ __launch_bounds__(256) void gn_stats(const float* __restrict__ x,
    float* __restrict__ part) {
  const int bg = blockIdx.x, sub = blockIdx.y;
  const float* xp = x + (size_t)bg * CPG * N_SP + (size_t)sub * (CPG * N_SP / 4);
  const int tid = threadIdx.x;
  float s = 0.f, ss = 0.f;
  for (int i = tid; i < CPG * N_SP / 4; i += 256) {
    float v = xp[i];
    s += v; ss += v * v;
  }
#pragma unroll
  for (int off = 32; off > 0; off >>= 1) {
    s  += __shfl_down(s, off);
    ss += __shfl_down(ss, off);
  }
  __shared__ float rs[4], rss[4];
  const int wv = tid >> 6, ln = tid & 63;
  if (ln == 0) { rs[wv] = s; rss[wv] = ss; }
  __syncthreads();
  if (tid == 0) {
    part[(bg * 4 + sub) * 2]     = rs[0] + rs[1] + rs[2] + rs[3];
    part[(bg * 4 + sub) * 2 + 1] = rss[0] + rss[1] + rss[2] + rss[3];
  }
}

// ---------------------------------------------------------------------------
// GroupNorm apply -> hT bf16 [B][N][C]. grid (64, 16): (bg, n-chunk of 256).
// ---------------------------------------------------------------------------
__global__ __launch_bounds__(256) void gn_apply(const float* __restrict__ x,
    const float* __restrict__ part, const float* __restrict__ w,
    const float* __restrict__ bgn, ushort_t* __restrict__ hT) {
  const int bg = blockIdx.x;
  const int b = bg >> 5, g = bg & 31;
  const int n0 = blockIdx.y * 256;
  const int tid = threadIdx.x;
  float S = 0.f, SS = 0.f;
#pragma unroll
  for (int i = 0; i < 4; ++i) {
    S  += part[(bg * 4 + i) * 2];
    SS += part[(bg * 4 + i) * 2 + 1];
  }
  const float mean = S / (float)(CPG * N_SP);
  const float var  = SS / (float)(CPG * N_SP) - mean * mean;
  const float rstd = rsqrtf(var + EPS_GN);
  float sc[8], sh[8];
#pragma unroll
  for (int c = 0; c < 8; ++c) {
    sc[c] = w[g * 8 + c] * rstd;
    sh[c] = bgn[g * 8 + c] - mean * sc[c];
  }
  __shared__ float tile[8][256];
  const float* xp = x + ((size_t)b * C_DIM + (size_t)g * CPG) * N_SP;
  for (int i = tid; i < 8 * 256; i += 256) {
    int cc = i >> 8, n = i & 255;
    tile[cc][n] = xp[(size_t)cc * N_SP + n0 + n];
  }
  __syncthreads();
  u32x4 pk4;
#pragma unroll
  for (int p = 0; p < 4; ++p)
    pk4[p] = pkbf(tile[2 * p][tid] * sc[2 * p] + sh[2 * p],
                  tile[2 * p + 1][tid] * sc[2 * p + 1] + sh[2 * p + 1]);
  *(u32x4*)&hT[((size_t)b * N_SP + n0 + tid) * C_DIM + g * 8] = pk4;
}

// ---------------------------------------------------------------------------
// MFMA GEMM, k-contiguous bf16 operands (verified round 4/5).
// ---------------------------------------------------------------------------
template <int MODE>
__global__ __launch_bounds__(256) void mgemm(
    const ushort_t* __restrict__ A, const ushort_t* __restrict__ Bm,
    const float* __restrict__ biasA, const float* __restrict__ biasB,
    ushort_t* __restrict__ outB, float* __restrict__ outF,
    const float* __restrict__ R, int aStride, int bStride, int ldo,
    size_t obStride) {
  __shared__ __align__(16) ushort_t a_lds[128 * 64];
  __shared__ __align__(16) ushort_t b_lds[128 * 64];
  const int bz = blockIdx.z;
  const ushort_t* Ab = A + (size_t)bz * aStride;
  const ushort_t* Bb = Bm + (size_t)bz * bStride;
  const int bm = blockIdx.y * 128, bn = blockIdx.x * 128;
  const int tid = threadIdx.x, wv = tid >> 6, ln = tid & 63;
  const int lo = ln & 15, g = ln >> 4;
  const int wr = wv >> 1, wc = wv & 1;

  f32x4 acc[4][4];
#pragma unroll
  for (int i = 0; i < 4; ++i)
#pragma unroll
    for (int j = 0; j < 4; ++j) acc[i][j] = (f32x4)(0.f);

  float bcol[4];
  float brow = 0.f;
  if (MODE == 0) {
#pragma unroll
    for (int ct = 0; ct < 4; ++ct) {
      int col = bn + wc * 64 + ct * 16 + lo;
      bcol[ct] = (col < 256) ? biasA[col] : biasB[col - 256];
    }
  } else {
    brow = biasA[bm + wr * 64 + ln];
  }

  for (int k0 = 0; k0 < C_DIM; k0 += 64) {
#pragma unroll
    for (int i = 0; i < 4; ++i) {
      int r0 = wv * 32 + i * 8;
      int row = r0 + (ln >> 3);
      GLOAD16(Ab + (size_t)(bm + row) * C_DIM + k0 + (((ln & 7) ^ (row & 7)) << 3),
              &a_lds[r0 * 64]);
      GLOAD16(Bb + (size_t)(bn + row) * C_DIM + k0 + (((ln & 7) ^ (row & 7)) << 3),
              &b_lds[r0 * 64]);
    }
    __syncthreads();
    bf16x8 af[4][2], bfr[4][2];
#pragma unroll
    for (int rt = 0; rt < 4; ++rt)
#pragma unroll
      for (int ks = 0; ks < 2; ++ks) {
        int row = wr * 64 + rt * 16 + lo;
        af[rt][ks] = *(const bf16x8*)&a_lds[row * 64 + (((ks * 4 + g) ^ (row & 7)) << 3)];
      }
#pragma unroll
    for (int ct = 0; ct < 4; ++ct)
#pragma unroll
      for (int ks = 0; ks < 2; ++ks) {
        int col = wc * 64 + ct * 16 + lo;
        bfr[ct][ks] = *(const bf16x8*)&b_lds[col * 64 + (((ks * 4 + g) ^ (col & 7)) << 3)];
      }
    __builtin_amdgcn_s_setprio(1);
#pragma unroll
    for (int ks = 0; ks < 2; ++ks)
#pragma unroll
      for (int rt = 0; rt < 4; ++rt)
#pragma unroll
        for (int ct = 0; ct < 4; ++ct)
          acc[rt][ct] = __builtin_amdgcn_mfma_f32_16x16x32_bf16(af[rt][ks], bfr[ct][ks], acc[rt][ct], 0, 0, 0);
    __builtin_amdgcn_s_setprio(0);
    __syncthreads();
  }

  float* wbase = (wv < 2 ? (float*)a_lds : (float*)b_lds) + (wv & 1) * 2048;
  const int grow = bm + wr * 64 + ln;
#pragma unroll
  for (int p = 0; p < 2; ++p) {
#pragma unroll
    for (int rt = 0; rt < 4; ++rt)
#pragma unroll
      for (int cth = 0; cth < 2; ++cth) {
        int ct = 2 * p + cth;
#pragma unroll
        for (int r = 0; r < 4; ++r) {
          int lrow = rt * 16 + 4 * g + r;
          int lcol = cth * 16 + lo;
          float v = acc[rt][ct][r];
          if (MODE == 0) v += bcol[ct];
          wbase[lrow * 32 + (lcol ^ ((lrow & 7) << 2))] = v;
        }
      }
    f32x4 buf[8];
#pragma unroll
    for (int cb = 0; cb < 8; ++cb) {
      int off = (4 * cb) ^ ((ln & 7) << 2);
      buf[cb] = *(const f32x4*)&wbase[ln * 32 + off];
    }
    const size_t obase = (size_t)grow * ldo + bn + wc * 64 + p * 32;
    if (MODE == 2) {
      const float* Rb = R + (size_t)bz * CN + obase;
      float* ob = outF + (size_t)bz * CN + obase;
#pragma unroll
      for (int cb = 0; cb < 8; ++cb) {
        f32x4 t = buf[cb];
        f32x4 rv = *(const f32x4*)&Rb[4 * cb];
#pragma unroll
        for (int j = 0; j < 4; ++j) t[j] += brow + rv[j];
        *(f32x4*)&ob[4 * cb] = t;
      }
    } else {
      float badd = (MODE == 0) ? 0.f : brow;
      ushort_t* ob = outB + (size_t)bz * obStride + obase;
      uint_t wpk[16];
#pragma unroll
      for (int k = 0; k < 16; ++k)
        wpk[k] = pkbf(buf[k >> 1][(k & 1) * 2] + badd, buf[k >> 1][(k & 1) * 2 + 1] + badd);
#pragma unroll
      for (int sidx = 0; sidx < 4; ++sidx) {
        u32x4 t;
        t[0] = wpk[4 * sidx]; t[1] = wpk[4 * sidx + 1];
        t[2] = wpk[4 * sidx + 2]; t[3] = wpk[4 * sidx + 3];
        *(u32x4*)&ob[sidx * 8] = t;
      }
    }
    __syncthreads();
  }
}

// ---------------------------------------------------------------------------
// MFMA flash attention v10 — as v9 (32x32x16, 32 q/wave, KT=64, dbuf K/V,
// one barrier/tile) with packed P-writes (8 x ds_write_b64 via cvt_pk)
// replacing 32 x ds_write_b16, and per-g2 exp processing (reg pressure).
// ---------------------------------------------------------------------------
__device__ __forceinline__ void stage_kv(const ushort_t* __restrict__ ktb,
    const ushort_t* __restrict__ vtb, int k0, ushort_t* kbuf, ushort_t* vbuf,
    int wv, int ln) {
#pragma unroll
  for (int i = 0; i < 8; ++i) {
    int m = wv * 16 + i * 2 + (ln >> 5);
    int sl = ln & 31;
    GLOAD16(ktb + (size_t)(k0 + m) * 512 + ((sl ^ (m & 7)) * 8),
            kbuf + (wv * 16 + i * 2) * 256);
  }
#pragma unroll
  for (int i = 0; i < 8; ++i) {
    int c = wv * 64 + i * 8 + (ln >> 3);
    int sl = ln & 7;
    GLOAD16(vtb + (size_t)c * N_SP + k0 + ((sl ^ (c & 7)) * 8),
            vbuf + (wv * 64 + i * 8) * 64);
  }
}

__global__ __launch_bounds__(256, 1) void attn_mfma(
    const ushort_t* __restrict__ qk, const ushort_t* __restrict__ vt,
    ushort_t* __restrict__ pO, float* __restrict__ pml) {
  // layout: k[2][64*256] | v[2][256*64] | p[4][32*72]  = 149504 B
  __shared__ __align__(16) ushort_t lds_all[32768 + 32768 + 9216];

  const int ksplit = blockIdx.y;
  const int b  = blockIdx.z;
  const int q0 = blockIdx.x * 128;
  const int tid = threadIdx.x;
  const int wv = tid >> 6;
  const int ln = tid & 63;
  const int lq = ln & 31;    // query column
  const int lh = ln >> 5;    // k-half selector

  const ushort_t* qtb = qk + (size_t)b * N_SP * 512;
  const ushort_t* ktb = qtb + 256;
  const ushort_t* vtb = vt + (size_t)b * CN;
  ushort_t* p_base = lds_all + 65536 + wv * (32 * 72);

  bf16x8 qf[16];
  {
    const ushort_t* qp = qtb + (size_t)(q0 + wv * 32 + lq) * 512 + lh * 8;
#pragma unroll
    for (int ks = 0; ks < 16; ++ks) qf[ks] = *(const bf16x8*)(qp + ks * 16);
  }

  f32x16 oac[8];
#pragma unroll
  for (int i = 0; i < 8; ++i) oac[i] = (f32x16)(0.f);
  float m_run = -1e30f, l_run = 0.f;

  const int kbase = ksplit * 1024;
  stage_kv(ktb, vtb, kbase, lds_all, lds_all + 32768, wv, ln);
  __syncthreads();   // implicit vmcnt(0): tile 0 resident

  for (int t = 0; t < 16; ++t) {
    const int cur = t & 1;
    ushort_t* kb = lds_all + cur * 16384;
    ushort_t* vb = lds_all + 32768 + cur * 16384;
    if (t + 1 < 16)
      stage_kv(ktb, vtb, kbase + (t + 1) * 64,
               lds_all + (cur ^ 1) * 16384,
               lds_all + 32768 + (cur ^ 1) * 16384, wv, ln);

    // ---- S^T = K Q^T : 2 key-subtiles x 16 k-steps (32 MFMA)
    f32x16 s0 = (f32x16)(0.f), s1 = (f32x16)(0.f);
    __builtin_amdgcn_s_setprio(1);
#pragma unroll
    for (int ks = 0; ks < 16; ++ks) {
      bf16x8 kf0 = *(const bf16x8*)&kb[(lq * 256 + ks * 16 + lh * 8) ^ ((lq & 7) << 3)];
      s0 = __builtin_amdgcn_mfma_f32_32x32x16_bf16(kf0, qf[ks], s0, 0, 0, 0);
      int m1 = 32 + lq;
      bf16x8 kf1 = *(const bf16x8*)&kb[(m1 * 256 + ks * 16 + lh * 8) ^ ((m1 & 7) << 3)];
      s1 = __builtin_amdgcn_mfma_f32_32x32x16_bf16(kf1, qf[ks], s1, 0, 0, 0);
    }
    __builtin_amdgcn_s_setprio(0);

    // ---- lane-local online softmax (query = lq)
    const float scale = 0.0625f;
    float mx[16];
#pragma unroll
    for (int r = 0; r < 16; ++r) mx[r] = fmaxf(s0[r], s1[r]);
#pragma unroll
    for (int r = 0; r < 8; ++r) mx[r] = fmaxf(mx[r], mx[r + 8]);
#pragma unroll
    for (int r = 0; r < 4; ++r) mx[r] = fmaxf(mx[r], mx[r + 4]);
    float pm = fmaxf(fmaxf(mx[0], mx[1]), fmaxf(mx[2], mx[3]));
    pm = fmaxf(pm, __shfl_xor(pm, 32));
    pm *= scale;
    float alpha = 1.f;
    if (!__all(pm <= m_run + 8.f)) {     // defer-max (THR=8)
      float mn = fmaxf(m_run, pm);
      alpha = __expf(m_run - mn);
      m_run = mn;
    }
    // per-g2: 8 exps live at once; pack 4 bf16 -> one ds_write_b64 per half.
    // key(r) for r in [4*g2, 4*g2+3] = 8*g2 + 4*lh + (r&3)  (contiguous 4)
    float rsum = 0.f;
#pragma unroll
    for (int g2 = 0; g2 < 4; ++g2) {
      float e00 = __expf(s0[4 * g2 + 0] * scale - m_run);
      float e01 = __expf(s0[4 * g2 + 1] * scale - m_run);
      float e02 = __expf(s0[4 * g2 + 2] * scale - m_run);
      float e03 = __expf(s0[4 * g2 + 3] * scale - m_run);
      float e10 = __expf(s1[4 * g2 + 0] * scale - m_run);
      float e11 = __expf(s1[4 * g2 + 1] * scale - m_run);
      float e12 = __expf(s1[4 * g2 + 2] * scale - m_run);
      float e13 = __expf(s1[4 * g2 + 3] * scale - m_run);
      rsum += ((e00 + e01) + (e02 + e03)) + ((e10 + e11) + (e12 + e13));
      uint2 wa; wa.x = pkbf(e00, e01); wa.y = pkbf(e02, e03);
      *(uint2*)&p_base[lq * 72 + 8 * g2 + 4 * lh] = wa;
      uint2 wb2; wb2.x = pkbf(e10, e11); wb2.y = pkbf(e12, e13);
      *(uint2*)&p_base[lq * 72 + 32 + 8 * g2 + 4 * lh] = wb2;
    }
    rsum += __shfl_xor(rsum, 32);
    l_run = l_run * alpha + rsum;
    if (!__all(alpha == 1.f)) {
#pragma unroll
      for (int i = 0; i < 8; ++i) oac[i] *= alpha;
    }

    // ---- PV: O^T = V^T P^T : 8 c-subtiles x 4 k-steps (32 MFMA)
    __builtin_amdgcn_s_setprio(1);
#pragma unroll
    for (int ks2 = 0; ks2 < 4; ++ks2) {
      bf16x8 pf = *(const bf16x8*)&p_base[lq * 72 + ks2 * 16 + lh * 8];
#pragma unroll
      for (int ot = 0; ot < 8; ++ot) {
        int c = ot * 32 + lq;
        bf16x8 vf = *(const bf16x8*)&vb[(c * 64 + ks2 * 16 + lh * 8) ^ ((c & 7) << 3)];
        oac[ot] = __builtin_amdgcn_mfma_f32_32x32x16_bf16(vf, pf, oac[ot], 0, 0, 0);
      }
    }
    __builtin_amdgcn_s_setprio(0);
    __syncthreads();   // drains stage(t+1) loads; fences buffer reuse
  }

  // ---- epilogue: per-wave 32KB fp32 scratch transpose (reuse k/v LDS)
  float* sb = (float*)lds_all + wv * 8192;
#pragma unroll
  for (int ot = 0; ot < 8; ++ot)
#pragma unroll
    for (int r = 0; r < 16; ++r) {
      int cl = (r & 3) + 8 * (r >> 2) + 4 * lh;
      int c = ot * 32 + cl;
      sb[lq * 256 + (c ^ ((lq & 7) << 2))] = oac[ot][r];
    }
  {
    const int q = ln >> 1, half = ln & 1;
    const size_t row32 = (((size_t)(ksplit * B_DIM + b) * N_SP) + q0 + wv * 32 + q) * 128;
    uint_t* pO32 = (uint_t*)pO;
#pragma unroll
    for (int j = 0; j < 32; ++j) {
      f32x4 v4 = *(const f32x4*)&sb[q * 256 + ((half * 128 + 4 * j) ^ ((q & 7) << 2))];
      uint2 pk2; pk2.x = pkbf(v4[0], v4[1]); pk2.y = pkbf(v4[2], v4[3]);
      *(uint2*)&pO32[row32 + half * 64 + 2 * j] = pk2;
    }
  }
  if (ln < 32) {
    int qn = q0 + wv * 32 + lq;
    size_t mi = (((size_t)(ksplit * B_DIM + b) * N_SP) + qn) * 2;
    pml[mi] = m_run;
    pml[mi + 1] = l_run;
  }
}

// ---------------------------------------------------------------------------
// Merge 4 split-K partials -> aoT bf16 [B][N][C].
// ---------------------------------------------------------------------------
__global__ __launch_bounds__(256) void merge_kernel(const ushort_t* __restrict__ pO,
    const float* __restrict__ pml, ushort_t* __restrict__ aoT) {
  const int b = blockIdx.y;
  const int n = blockIdx.x * 16 + (threadIdx.x >> 4);
  const int cg = threadIdx.x & 15;
  float mi[4], li[4];
#pragma unroll
  for (int i = 0; i < 4; ++i) {
    size_t o = (((size_t)(i * B_DIM + b) * N_SP) + n) * 2;
    mi[i] = pml[o]; li[i] = pml[o + 1];
  }
  float ms = fmaxf(fmaxf(mi[0], mi[1]), fmaxf(mi[2], mi[3]));
  float wsum = 0.f, wi[4];
#pragma unroll
  for (int i = 0; i < 4; ++i) { wi[i] = __expf(mi[i] - ms); wsum += wi[i] * li[i]; }
  float inv = 1.f / wsum;
  float acc[16] = {};
#pragma unroll
  for (int i = 0; i < 4; ++i) {
    const ushort_t* p = pO + (((size_t)(i * B_DIM + b) * N_SP) + n) * C_DIM + cg * 16;
    u32x4 a = *(const u32x4*)p;
    u32x4 c2 = *(const u32x4*)(p + 8);
#pragma unroll
    for (int j = 0; j < 4; ++j) {
      acc[2 * j]     += wi[i] * bf2f(a[j] & 0xffffu);
      acc[2 * j + 1] += wi[i] * bf2f(a[j] >> 16);
      acc[8 + 2 * j]     += wi[i] * bf2f(c2[j] & 0xffffu);
      acc[8 + 2 * j + 1] += wi[i] * bf2f(c2[j] >> 16);
    }
  }
  ushort_t* ob = aoT + ((size_t)b * N_SP + n) * C_DIM + cg * 16;
  u32x4 o0, o1;
#pragma unroll
  for (int k = 0; k < 4; ++k) o0[k] = pkbf(acc[2 * k] * inv, acc[2 * k + 1] * inv);
#pragma unroll
  for (int k = 0; k < 4; ++k) o1[k] = pkbf(acc[8 + 2 * k] * inv, acc[8 + 2 * k + 1] * inv);
  *(u32x4*)&ob[0] = o0;
  *(u32x4*)&ob[8] = o1;
}

// ---------------------------------------------------------------------------
extern "C" void kernel_launch(void* const* d_in, const int* in_sizes, int n_in,
                              void* d_out, int out_size, void* d_ws, size_t ws_size,
                              hipStream_t stream) {
  const float* x   = (const float*)d_in[0];
  const float* gnw = (const float*)d_in[1];
  const float* gnb = (const float*)d_in[2];
  const float* wq  = (const float*)d_in[3];
  const float* bq  = (const float*)d_in[4];
  const float* wk  = (const float*)d_in[5];
  const float* bk  = (const float*)d_in[6];
  const float* wv  = (const float*)d_in[7];
  const float* bv  = (const float*)d_in[8];
  const float* wp  = (const float*)d_in[9];
  const float* bp  = (const float*)d_in[10];
  float* out = (float*)d_out;

  // ws (bytes): hT 4M | wb 0.5M | qk 8M | vN 4M | aoT 4M | pml 0.25M | pO 16M | gnp
  char* w8 = (char*)d_ws;
  ushort_t* hT  = (ushort_t*)(w8);
  ushort_t* wb  = (ushort_t*)(w8 + (4u << 20));
  ushort_t* qkw = (ushort_t*)(w8 + (4u << 20) + (1u << 19));
  ushort_t* vN  = (ushort_t*)(w8 + (12u << 20) + (1u << 19));
  ushort_t* aoT = (ushort_t*)(w8 + (16u << 20) + (1u << 19));
  float*    pml = (float*)(w8 + (20u << 20) + (1u << 19));
  ushort_t* pO  = (ushort_t*)(w8 + (20u << 20) + (1u << 19) + (1u << 18));
  float*    gnp = (float*)(w8 + (36u << 20) + (1u << 19) + (1u << 18));

  ushort_t* wvb = wb + 131072;
  ushort_t* wpb = wb + 196608;

  wcvt_kernel<<<dim3(256), dim3(256), 0, stream>>>(wq, wk, wv, wp, wb);
  gn_stats<<<dim3(B_DIM * 32, 4), dim3(256), 0, stream>>>(x, gnp);
  gn_apply<<<dim3(B_DIM * 32, 16), dim3(256), 0, stream>>>(x, gnp, gnw, gnb, hT);

  mgemm<0><<<dim3(4, 32, B_DIM), dim3(256), 0, stream>>>(
      hT, wb, bq, bk, qkw, nullptr, nullptr, (int)CN, 0, 512, (size_t)N_SP * 512);
  mgemm<1><<<dim3(32, 2, B_DIM), dim3(256), 0, stream>>>(
      wvb, hT, bv, nullptr, vN, nullptr, nullptr, 0, (int)CN, N_SP, CN);

  attn_mfma<<<dim3(32, 4, B_DIM), dim3(256), 0, stream>>>(qkw, vN, pO, pml);
  merge_kernel<<<dim3(256, B_DIM), dim3(256), 0, stream>>>(pO, pml, aoT);

  mgemm<2><<<dim3(32, 2, B_DIM), dim3(256), 0, stream>>>(
      wpb, aoT, bp, nullptr, nullptr, out, x, 0, (int)CN, N_SP, CN);
}